// Round 8
// baseline (746.217 us; speedup 1.0000x reference)
//
#include <hip/hip_runtime.h>
#include <cstdint>
#include <cstddef>

#define N_IN  700
#define N_INP 704           // K padded to 32
#define N_HID 512
#define N_OUT 20
#define BB    256
#define TT    100
#define NK    (BB*TT)       // 25600
#define NCH   8             // split-k chunks for gf/gr
#define GOCH  32            // k-chunks for goF

__device__ __constant__ const float TAU   = 0.6f;
__device__ __constant__ const float TAU_O = 0.6f;
__device__ __constant__ const float THR   = 0.6f;
__device__ __constant__ const float GAM   = 0.3f;

typedef float f32x4 __attribute__((ext_vector_type(4)));
typedef __bf16 bf16x8 __attribute__((ext_vector_type(8)));

__device__ __forceinline__ unsigned short f2bf_rne(float f) {
  uint32_t b = __builtin_bit_cast(uint32_t, f);
  uint32_t r = (b + 0x7FFFu + ((b >> 16) & 1u)) >> 16;
  return (unsigned short)r;
}
__device__ __forceinline__ float bf2f(unsigned short u) {
  uint32_t b = ((uint32_t)u) << 16;
  return __builtin_bit_cast(float, b);
}

// ---------------- prep: W split into hi+lo bf16, [r][i] layout padded to 704 ----------------
__global__ void k_wsplit(const float* __restrict__ W1,
                         unsigned short* __restrict__ WH,
                         unsigned short* __restrict__ WL) {
  int g = blockIdx.x*256 + threadIdx.x;
  if (g >= N_HID*88) return;
  int r = g / 88, c = g - (g/88)*88;
  int ib = c*8;
  unsigned short h[8], l[8];
  #pragma unroll
  for (int j = 0; j < 8; ++j) {
    int i = ib + j;
    float v = (i < N_IN) ? W1[r*N_IN + i] : 0.f;
    unsigned short hh = f2bf_rne(v);
    float res = v - bf2f(hh);
    h[j] = hh;
    l[j] = f2bf_rne(res);
  }
  uint4 hv = make_uint4((uint32_t)h[0] | ((uint32_t)h[1]<<16), (uint32_t)h[2] | ((uint32_t)h[3]<<16),
                        (uint32_t)h[4] | ((uint32_t)h[5]<<16), (uint32_t)h[6] | ((uint32_t)h[7]<<16));
  uint4 lv = make_uint4((uint32_t)l[0] | ((uint32_t)l[1]<<16), (uint32_t)l[2] | ((uint32_t)l[3]<<16),
                        (uint32_t)l[4] | ((uint32_t)l[5]<<16), (uint32_t)l[6] | ((uint32_t)l[7]<<16));
  *(uint4*)(WH + (size_t)r*N_INP + ib) = hv;
  *(uint4*)(WL + (size_t)r*N_INP + ib) = lv;
}

__global__ void k_prep_t2(const float* __restrict__ Wr, float* __restrict__ WRT) {
  int g = blockIdx.x*256 + threadIdx.x;
  if (g < N_HID*N_HID) {
    int j = g >> 9, r = g & 511;
    WRT[g] = Wr[r*N_HID + j];
  }
}
// NOTE: summation order of Srow/SOs is spike-determining — keep serial order exactly.
__global__ void k_prep_sums(const float* __restrict__ Wr, const float* __restrict__ Wo,
                            float* __restrict__ Srow, float* __restrict__ SOs,
                            int* __restrict__ tmax) {
  int g = blockIdx.x*256 + threadIdx.x;
  if (g < N_HID) {
    float s = 0.f;
    for (int j = 0; j < N_HID; ++j) s += Wr[g*N_HID + j];
    Srow[g] = s;
  } else if (g < N_HID + N_OUT) {
    int o = g - N_HID;
    float s = 0.f;
    for (int r = 0; r < N_HID; ++r) s += Wo[o*N_HID + r];
    SOs[o] = s;
  }
  if (g < BB) tmax[g] = 0;
}

// ---------------- phase A: INL = X @ (WH^T + WL^T), MFMA split-bf16 ----------------
__global__ __launch_bounds__(256) void k_gemm(const float* __restrict__ x,
                                              const unsigned short* __restrict__ WH,
                                              const unsigned short* __restrict__ WL,
                                              float* __restrict__ INL) {
  __shared__ __align__(16) unsigned short sA [128*32];
  __shared__ __align__(16) unsigned short sBh[128*32];
  __shared__ __align__(16) unsigned short sBl[128*32];
  const int tid = threadIdx.x, lane = tid & 63, w = tid >> 6;
  const int k0 = blockIdx.x * 128;
  const int c0 = blockIdx.y * 128;
  const int wr = w >> 1, wc = w & 1;
  const int fr = lane & 15, fk = lane >> 4;

  const int a_r  = tid >> 1;
  const int a_cb = (tid & 1) * 16;
  const int b_r  = tid >> 2;
  const int b_c  = (tid & 3) * 8;

  const float* xr = x + (size_t)(k0 + a_r) * N_IN;
  const unsigned short* gh = WH + (size_t)(c0 + b_r) * N_INP;
  const unsigned short* gl = WL + (size_t)(c0 + b_r) * N_INP;

  f32x4 acc[4][4];
  #pragma unroll
  for (int m = 0; m < 4; ++m)
    #pragma unroll
    for (int n = 0; n < 4; ++n)
      acc[m][n] = (f32x4){0.f, 0.f, 0.f, 0.f};

  for (int s = 0; s < N_INP/32; ++s) {
    const int i0 = s * 32;
    float av[16];
    const int col0 = i0 + a_cb;
    if (col0 + 16 <= N_IN) {
      float4 t0 = *(const float4*)(xr + col0);
      float4 t1 = *(const float4*)(xr + col0 + 4);
      float4 t2 = *(const float4*)(xr + col0 + 8);
      float4 t3 = *(const float4*)(xr + col0 + 12);
      av[0]=t0.x; av[1]=t0.y; av[2]=t0.z; av[3]=t0.w;
      av[4]=t1.x; av[5]=t1.y; av[6]=t1.z; av[7]=t1.w;
      av[8]=t2.x; av[9]=t2.y; av[10]=t2.z; av[11]=t2.w;
      av[12]=t3.x; av[13]=t3.y; av[14]=t3.z; av[15]=t3.w;
    } else {
      #pragma unroll
      for (int j = 0; j < 16; ++j) av[j] = (col0 + j < N_IN) ? xr[col0 + j] : 0.f;
    }
    uint32_t us[8];
    #pragma unroll
    for (int p = 0; p < 8; ++p) {
      uint32_t lo = __builtin_bit_cast(uint32_t, av[2*p])   >> 16;
      uint32_t hi = __builtin_bit_cast(uint32_t, av[2*p+1]) & 0xFFFF0000u;
      us[p] = hi | lo;
    }
    *(uint4*)&sA[a_r*32 + a_cb]     = make_uint4(us[0], us[1], us[2], us[3]);
    *(uint4*)&sA[a_r*32 + a_cb + 8] = make_uint4(us[4], us[5], us[6], us[7]);
    *(uint4*)&sBh[b_r*32 + b_c]      = *(const uint4*)(gh + i0 + b_c);
    *(uint4*)&sBh[(b_r+64)*32 + b_c] = *(const uint4*)(gh + (size_t)64*N_INP + i0 + b_c);
    *(uint4*)&sBl[b_r*32 + b_c]      = *(const uint4*)(gl + i0 + b_c);
    *(uint4*)&sBl[(b_r+64)*32 + b_c] = *(const uint4*)(gl + (size_t)64*N_INP + i0 + b_c);
    __syncthreads();

    bf16x8 a[4], bh[4], bl[4];
    #pragma unroll
    for (int m = 0; m < 4; ++m)
      a[m] = *(const bf16x8*)&sA[(wr*64 + m*16 + fr)*32 + fk*8];
    #pragma unroll
    for (int n = 0; n < 4; ++n) {
      bh[n] = *(const bf16x8*)&sBh[(wc*64 + n*16 + fr)*32 + fk*8];
      bl[n] = *(const bf16x8*)&sBl[(wc*64 + n*16 + fr)*32 + fk*8];
    }
    #pragma unroll
    for (int m = 0; m < 4; ++m)
      #pragma unroll
      for (int n = 0; n < 4; ++n) {
        acc[m][n] = __builtin_amdgcn_mfma_f32_16x16x32_bf16(a[m], bh[n], acc[m][n], 0, 0, 0);
        acc[m][n] = __builtin_amdgcn_mfma_f32_16x16x32_bf16(a[m], bl[n], acc[m][n], 0, 0, 0);
      }
    __syncthreads();
  }
  #pragma unroll
  for (int m = 0; m < 4; ++m) {
    #pragma unroll
    for (int n = 0; n < 4; ++n) {
      #pragma unroll
      for (int reg = 0; reg < 4; ++reg) {
        const int row = k0 + wr*64 + m*16 + (lane>>4)*4 + reg;
        const int col = c0 + wc*64 + n*16 + fr;
        INL[(size_t)row*N_HID + col] = acc[m][n][reg];
      }
    }
  }
}

// ---------------- phase B: one WAVE per batch row — no barriers, no LDS ----------------
// lane owns neurons r = j*64+lane (j=0..7); output neuron o = lane (lane<20).
// Stores: h'(hm) into INL (in place), spike masks, outs, err. L/go computed later.
__global__ __launch_bounds__(64) void k_scan(
    float* __restrict__ INL, const float* __restrict__ label,
    const float* __restrict__ Wo, const float* __restrict__ WRT,
    const float* __restrict__ Srow, const float* __restrict__ SOs,
    unsigned long long* __restrict__ hsbits, float* __restrict__ outs,
    float* __restrict__ errb)
{
  const int b = blockIdx.x, lane = threadIdx.x;
  const size_t base = (size_t)b*TT;
  float srw[8], hm[8], curv[8], nxtv[8];
  int hs[8];
  #pragma unroll
  for (int j = 0; j < 8; ++j) { srw[j] = Srow[j*64 + lane]; hm[j] = 0.f; hs[j] = 0; }
  #pragma unroll
  for (int j = 0; j < 8; ++j) curv[j] = INL[base*N_HID + j*64 + lane];
  #pragma unroll
  for (int j = 0; j < 8; ++j) nxtv[j] = INL[(base+1)*N_HID + j*64 + lane];
  const float SOsl = (lane < N_OUT) ? SOs[lane] : 0.f;
  float lab = (lane < N_OUT) ? label[base*N_OUT + lane] : 0.f;
  float om = 0.f; int osb = 0;
  unsigned long long mp[8]; int ctotp = 0;
  #pragma unroll
  for (int j = 0; j < 8; ++j) mp[j] = 0ULL;

  for (int t = 0; t < TT; ++t) {
    const size_t k = base + t;
    // 2-deep prefetch of IN, 1-deep of label
    float nn[8];
    const size_t k2 = (t + 2 < TT) ? (k + 2) : (base + TT - 1);
    #pragma unroll
    for (int j = 0; j < 8; ++j) nn[j] = INL[k2*N_HID + j*64 + lane];
    const size_t k1 = (t + 1 < TT) ? (k + 1) : k;
    const float labn = (lane < N_OUT) ? label[k1*N_OUT + lane] : 0.f;

    // recurrent drive (prev-step masks, wave-uniform control)
    float rec[8];
    if (ctotp == 512) {
      #pragma unroll
      for (int j = 0; j < 8; ++j) rec[j] = srw[j];
    } else if (ctotp == 0) {
      #pragma unroll
      for (int j = 0; j < 8; ++j) rec[j] = 0.f;
    } else {
      const int modep = (ctotp <= 256) ? 0 : 1;
      float racc[8];
      #pragma unroll
      for (int j = 0; j < 8; ++j) racc[j] = 0.f;
      for (int q = 0; q < 8; ++q) {
        unsigned long long mm = modep ? ~mp[q] : mp[q];
        while (mm) {
          const int j2 = __ffsll((long long)mm) - 1; mm &= (mm - 1ULL);
          const int jj = q*64 + j2;
          #pragma unroll
          for (int j = 0; j < 8; ++j) racc[j] += WRT[jj*N_HID + j*64 + lane];
        }
      }
      #pragma unroll
      for (int j = 0; j < 8; ++j) rec[j] = modep ? (srw[j] - racc[j]) : racc[j];
    }

    // hidden membrane + spikes
    float nhm[8]; int nhs[8]; unsigned long long m[8];
    #pragma unroll
    for (int j = 0; j < 8; ++j)
      nhm[j] = TAU*hm[j]*(hs[j] ? 0.f : 1.f) + curv[j] + rec[j];
    #pragma unroll
    for (int j = 0; j < 8; ++j) { nhs[j] = (nhm[j] >= THR) ? 1 : 0; m[j] = __ballot(nhs[j] != 0); }
    int ctot = 0;
    #pragma unroll
    for (int j = 0; j < 8; ++j) ctot += (int)__popcll(m[j]);
    if (lane == 0) {
      #pragma unroll
      for (int j = 0; j < 8; ++j) hsbits[k*8 + j] = m[j];
    }

    // output drive (o = lane)
    float drv;
    if (ctot == 512) drv = SOsl;
    else if (ctot == 0) drv = 0.f;
    else {
      const int mode = (ctot <= 256) ? 0 : 1;
      float cdr = 0.f;
      for (int q = 0; q < 8; ++q) {
        unsigned long long mm = mode ? ~m[q] : m[q];
        while (mm) {
          const int j2 = __ffsll((long long)mm) - 1; mm &= (mm - 1ULL);
          const int jj = q*64 + j2;
          if (lane < N_OUT) cdr += Wo[lane*N_HID + jj];
        }
      }
      drv = mode ? (SOsl - cdr) : cdr;
    }

    // output neuron update (scalar per lane)
    om = TAU*om*(osb ? 0.f : 1.f) + drv;
    const int nos = (om >= THR) ? 1 : 0;
    if (lane < N_OUT) {
      const float osf = nos ? 1.f : 0.f;
      outs[k*N_OUT + lane] = osf;
      errb[k*N_OUT + lane] = osf - lab;
    }
    osb = nos;

    // h' store (in place over IN)
    #pragma unroll
    for (int j = 0; j < 8; ++j) {
      const float a  = fabsf(nhm[j] - THR) / THR;
      const float ht = GAM * fmaxf(0.f, 1.f - a);
      INL[k*N_HID + j*64 + lane] = ht;
      hm[j] = nhm[j]; hs[j] = nhs[j];
    }
    #pragma unroll
    for (int j = 0; j < 8; ++j) { curv[j] = nxtv[j]; nxtv[j] = nn[j]; mp[j] = m[j]; }
    ctotp = ctot;
    lab = labn;
  }
}

// ---------------- phase C1: F_s[o] = err_s[o] + TAU_O * F_{s+1}[o] ----------------
__global__ void k_ffilt(const float* __restrict__ errb, float* __restrict__ F) {
  const int g = blockIdx.x*256 + threadIdx.x;      // 5120 threads (b,o)
  if (g >= BB*N_OUT) return;
  const int b = g / N_OUT, o = g - b*N_OUT;
  float f = 0.f;
  float cur = errb[((size_t)b*TT + TT - 1)*N_OUT + o];
  for (int t = TT - 1; t >= 0; --t) {
    const float nxt = (t > 0) ? errb[((size_t)b*TT + t - 1)*N_OUT + o] : 0.f;
    f = cur + TAU_O*f;
    F[((size_t)b*TT + t)*N_OUT + o] = f;
    cur = nxt;
  }
}

// ---------------- phase C2: fused L = (err@Wo)*h' and reverse filter M, in place ----------------
__global__ __launch_bounds__(256) void k_mfilter(float* __restrict__ INL,
                                                 const float* __restrict__ errb,
                                                 const float* __restrict__ Wo,
                                                 int* __restrict__ tmax) {
  const int g = blockIdx.x*256 + threadIdx.x;      // (b, r)
  const int b = g >> 9, r = g & 511;
  float woc[N_OUT];
  #pragma unroll
  for (int o = 0; o < N_OUT; ++o) woc[o] = Wo[o*N_HID + r];
  const size_t rb = (size_t)b*TT;
  float mval = 0.f; int last = -1;
  float hcur = INL[(rb + TT - 1)*N_HID + r];
  for (int t = TT - 1; t >= 0; --t) {
    const float hnxt = (t > 0) ? INL[(rb + t - 1)*N_HID + r] : 0.f;
    float d = 0.f;
    #pragma unroll
    for (int o = 0; o < N_OUT; ++o) d += errb[(rb + t)*N_OUT + o] * woc[o];
    const float v = d*hcur + TAU*mval;
    INL[(rb + t)*N_HID + r] = v;
    mval = v;
    if (v != 0.f && last < 0) last = t;
    hcur = hnxt;
  }
  if (last >= 0) atomicMax(tmax + b, last + 1);
}

// ---------------- phase D: go partials via spike-gated F sums ----------------
__global__ __launch_bounds__(256) void k_goF(const unsigned long long* __restrict__ hsbits,
                                             const float* __restrict__ F,
                                             float* __restrict__ goFp) {
  const int lane = threadIdx.x & 63, w = threadIdx.x >> 6;
  const int rw = blockIdx.x;                        // 8 r-words
  const int ch = blockIdx.y;                        // GOCH chunks
  float acc[5];
  #pragma unroll
  for (int i = 0; i < 5; ++i) acc[i] = 0.f;
  const int kpc = NK/GOCH;
  const int k0 = ch*kpc, k1 = k0 + kpc;
  for (int k = k0; k < k1; ++k) {
    const unsigned long long word = hsbits[(size_t)k*8 + rw];
    const int bit = (int)((word >> lane) & 1ULL);
    #pragma unroll
    for (int i = 0; i < 5; ++i) {
      const float fv = F[(size_t)k*N_OUT + w*5 + i];
      acc[i] += bit ? fv : 0.f;
    }
  }
  #pragma unroll
  for (int i = 0; i < 5; ++i)
    goFp[(size_t)ch*(N_OUT*N_HID) + (size_t)(w*5 + i)*N_HID + rw*64 + lane] = acc[i];
}
__global__ void k_gored(const float* __restrict__ goFp, float* __restrict__ go) {
  const int g = blockIdx.x*256 + threadIdx.x;
  if (g < N_OUT*N_HID) {
    float s = 0.f;
    #pragma unroll
    for (int c = 0; c < GOCH; ++c) s += goFp[(size_t)c*(N_OUT*N_HID) + g];
    go[g] = 0.1f*s;
  }
}

// ---------------- phase D: gf partials over b-chunks ----------------
__global__ __launch_bounds__(256) void k_gf(const float* __restrict__ M, const float* __restrict__ x,
                                            const int* __restrict__ tmax,
                                            float* __restrict__ gfp) {
  const int lane = threadIdx.x & 63, w = threadIdx.x >> 6;
  const int r  = blockIdx.x*64 + lane;
  const int i0 = blockIdx.y*64 + w*16;
  const int ch = blockIdx.z;
  const int b_lo = ch * (BB/NCH);
  __shared__ int cnt_sh[BB/NCH];
  if (threadIdx.x < BB/NCH) cnt_sh[threadIdx.x] = tmax[b_lo + threadIdx.x];
  __syncthreads();
  float acc[16];
  #pragma unroll
  for (int ii = 0; ii < 16; ++ii) acc[ii] = 0.f;
  int xi = i0 + (lane & 15); if (xi > N_IN - 1) xi = N_IN - 1;
  for (int bi = 0; bi < BB/NCH; ++bi) {
    const int ct = cnt_sh[bi];
    if (ct == 0) continue;
    const size_t kb = (size_t)(b_lo + bi)*TT;
    float mv = M[kb*N_HID + r];
    float xv = x[kb*N_IN + xi];
    for (int t = 0; t < ct; ++t) {
      float mv_n = 0.f, xv_n = 0.f;
      if (t + 1 < ct) {
        mv_n = M[(kb + t + 1)*N_HID + r];
        xv_n = x[(kb + t + 1)*N_IN + xi];
      }
      #pragma unroll
      for (int ii = 0; ii < 16; ++ii) acc[ii] += mv * __shfl(xv, ii);
      mv = mv_n; xv = xv_n;
    }
  }
  #pragma unroll
  for (int ii = 0; ii < 16; ++ii) {
    const int i = i0 + ii;
    if (i < N_IN) gfp[(size_t)ch*(N_HID*N_IN) + (size_t)r*N_IN + i] = acc[ii];
  }
}

// ---------------- phase D: gr partials over b-chunks ----------------
__global__ __launch_bounds__(256) void k_gr(const float* __restrict__ M,
                                            const unsigned long long* __restrict__ hsbits,
                                            const int* __restrict__ tmax,
                                            float* __restrict__ grp) {
  const int lane = threadIdx.x & 63, w = threadIdx.x >> 6;
  const int r  = blockIdx.x*64 + lane;
  const int h0 = blockIdx.y*64 + w*16;
  const int ch = blockIdx.z;
  const int b_lo = ch * (BB/NCH);
  __shared__ int cnt_sh[BB/NCH];
  if (threadIdx.x < BB/NCH) cnt_sh[threadIdx.x] = tmax[b_lo + threadIdx.x];
  __syncthreads();
  float acc[16];
  #pragma unroll
  for (int ii = 0; ii < 16; ++ii) acc[ii] = 0.f;
  const int hw = h0 >> 6, sh = h0 & 63;
  for (int bi = 0; bi < BB/NCH; ++bi) {
    const int ct = cnt_sh[bi];
    if (ct == 0) continue;
    const size_t kb = (size_t)(b_lo + bi)*TT;
    float mv = M[kb*N_HID + r];
    unsigned long long word = hsbits[kb*8 + hw];
    for (int t = 0; t < ct; ++t) {
      float mv_n = 0.f; unsigned long long word_n = 0ULL;
      if (t + 1 < ct) {
        mv_n = M[(kb + t + 1)*N_HID + r];
        word_n = hsbits[(kb + t + 1)*8 + hw];
      }
      #pragma unroll
      for (int ii = 0; ii < 16; ++ii)
        if ((word >> (sh + ii)) & 1ULL) acc[ii] += mv;
      mv = mv_n; word = word_n;
    }
  }
  #pragma unroll
  for (int ii = 0; ii < 16; ++ii)
    grp[(size_t)ch*(N_HID*N_HID) + (size_t)r*N_HID + h0 + ii] = acc[ii];
}

// ---------------- phase D: deterministic partial reductions ----------------
__global__ void k_gfred(const float* __restrict__ gfp, float* __restrict__ gf) {
  const int g = blockIdx.x*256 + threadIdx.x;
  if (g < N_HID*N_IN) {
    float s = 0.f;
    #pragma unroll
    for (int c = 0; c < NCH; ++c) s += gfp[(size_t)c*(N_HID*N_IN) + g];
    gf[g] = 0.1f*s;
  }
}
__global__ void k_grred(const float* __restrict__ grp, float* __restrict__ gr) {
  const int g = blockIdx.x*256 + threadIdx.x;
  if (g < N_HID*N_HID) {
    float s = 0.f;
    #pragma unroll
    for (int c = 0; c < NCH; ++c) s += grp[(size_t)c*(N_HID*N_HID) + g];
    gr[g] = 0.1f*s;
  }
}

extern "C" void kernel_launch(void* const* d_in, const int* in_sizes, int n_in,
                              void* d_out, int out_size, void* d_ws, size_t ws_size,
                              hipStream_t stream) {
  const float* x     = (const float*)d_in[0];
  const float* label = (const float*)d_in[1];
  const float* W1    = (const float*)d_in[2];
  const float* Wr    = (const float*)d_in[3];
  const float* Wo    = (const float*)d_in[4];

  float* out  = (float*)d_out;
  float* outs = out;                                    // [256][100][20]
  float* gf   = out + 512000;                           // [512][700]
  float* gr   = out + 512000 + 358400;                  // [512][512]
  float* go   = out + 512000 + 358400 + 262144;         // [20][512]

  char* ws = (char*)d_ws;
  size_t off = 0;
  auto alloc = [&](size_t bytes) -> char* {
    char* p = ws + off;
    off += (bytes + 255) & ~(size_t)255;
    return p;
  };
  float* INL = (float*)alloc((size_t)NK*N_HID*sizeof(float));                    // 52.43 MB
  unsigned long long* hsb = (unsigned long long*)alloc((size_t)NK*8*sizeof(unsigned long long)); // 1.64 MB
  int* tmax = (int*)alloc((size_t)BB*sizeof(int));
  char* uni = alloc((size_t)20971520);                                           // 20 MB union region

  // lifetime-overlapped residents of uni:
  float* F    = (float*)(uni);                          // 2.05 MB  (ffilt -> goF; dead before k_gf)
  float* errb = (float*)(uni + 2621440);                // 2.05 MB  (scan -> mfilter; dead before k_gf)
  unsigned short* WH = (unsigned short*)(uni + 4718592);// 0.72 MB  (dead after gemm)
  unsigned short* WL = (unsigned short*)(uni + 5439488);// 0.72 MB  (dead after gemm)
  float* WRT  = (float*)(uni + 6160384);                // 1.05 MB  (dead after scan)
  float* Srow = (float*)(uni + 7208960);                //          (dead after scan)
  float* SOs  = (float*)(uni + 7211008);                //          (dead after scan)
  // late residents:
  float* gfp  = (float*)(uni);                          // 11.47 MB (k_gf, clobbers F/errb/WH/WL/WRT)
  float* grp  = (float*)(uni + 11468800);               // 8.39 MB  (k_gr, clobbers goFp)
  float* goFp = (float*)(uni + 11468800);               // 1.31 MB  (goF -> gored, before k_gr)

  k_wsplit<<<(N_HID*88 + 255)/256, 256, 0, stream>>>(W1, WH, WL);
  k_prep_t2<<<(N_HID*N_HID + 255)/256, 256, 0, stream>>>(Wr, WRT);
  k_prep_sums<<<(N_HID + N_OUT + 255)/256, 256, 0, stream>>>(Wr, Wo, Srow, SOs, tmax);
  dim3 gg(NK/128, N_HID/128);
  k_gemm<<<gg, 256, 0, stream>>>(x, WH, WL, INL);
  k_scan<<<BB, 64, 0, stream>>>(INL, label, Wo, WRT, Srow, SOs, hsb, outs, errb);
  k_ffilt<<<(BB*N_OUT + 255)/256, 256, 0, stream>>>(errb, F);
  k_mfilter<<<(BB*N_HID)/256, 256, 0, stream>>>(INL, errb, Wo, tmax);
  dim3 ggo(8, GOCH);
  k_goF<<<ggo, 256, 0, stream>>>(hsb, F, goFp);
  k_gored<<<(N_OUT*N_HID + 255)/256, 256, 0, stream>>>(goFp, go);
  dim3 ggf(8, 11, NCH); k_gf<<<ggf, 256, 0, stream>>>(INL, x, tmax, gfp);
  dim3 ggr(8, 8, NCH);  k_gr<<<ggr, 256, 0, stream>>>(INL, hsb, tmax, grp);
  k_gfred<<<(N_HID*N_IN + 255)/256, 256, 0, stream>>>(gfp, gf);
  k_grred<<<(N_HID*N_HID + 255)/256, 256, 0, stream>>>(grp, gr);
}

// Round 9
// 576.509 us; speedup vs baseline: 1.2944x; 1.2944x over previous
//
#include <hip/hip_runtime.h>
#include <cstdint>
#include <cstddef>

#define N_IN  700
#define N_INP 704           // K padded to 32
#define N_HID 512
#define N_OUT 20
#define BB    256
#define TT    100
#define NK    (BB*TT)       // 25600
#define NCH   8             // split-k chunks for gf/gr

__device__ __constant__ const float TAU   = 0.6f;
__device__ __constant__ const float TAU_O = 0.6f;
__device__ __constant__ const float THR   = 0.6f;
__device__ __constant__ const float GAM   = 0.3f;

typedef float f32x4 __attribute__((ext_vector_type(4)));
typedef __bf16 bf16x8 __attribute__((ext_vector_type(8)));

__device__ __forceinline__ unsigned short f2bf_rne(float f) {
  uint32_t b = __builtin_bit_cast(uint32_t, f);
  uint32_t r = (b + 0x7FFFu + ((b >> 16) & 1u)) >> 16;
  return (unsigned short)r;
}
__device__ __forceinline__ float bf2f(unsigned short u) {
  uint32_t b = ((uint32_t)u) << 16;
  return __builtin_bit_cast(float, b);
}

// ---------------- prep: W split into hi+lo bf16, [r][i] layout padded to 704 ----------------
__global__ void k_wsplit(const float* __restrict__ W1,
                         unsigned short* __restrict__ WH,
                         unsigned short* __restrict__ WL) {
  int g = blockIdx.x*256 + threadIdx.x;
  if (g >= N_HID*88) return;
  int r = g / 88, c = g - (g/88)*88;
  int ib = c*8;
  unsigned short h[8], l[8];
  #pragma unroll
  for (int j = 0; j < 8; ++j) {
    int i = ib + j;
    float v = (i < N_IN) ? W1[r*N_IN + i] : 0.f;
    unsigned short hh = f2bf_rne(v);
    float res = v - bf2f(hh);
    h[j] = hh;
    l[j] = f2bf_rne(res);
  }
  uint4 hv = make_uint4((uint32_t)h[0] | ((uint32_t)h[1]<<16), (uint32_t)h[2] | ((uint32_t)h[3]<<16),
                        (uint32_t)h[4] | ((uint32_t)h[5]<<16), (uint32_t)h[6] | ((uint32_t)h[7]<<16));
  uint4 lv = make_uint4((uint32_t)l[0] | ((uint32_t)l[1]<<16), (uint32_t)l[2] | ((uint32_t)l[3]<<16),
                        (uint32_t)l[4] | ((uint32_t)l[5]<<16), (uint32_t)l[6] | ((uint32_t)l[7]<<16));
  *(uint4*)(WH + (size_t)r*N_INP + ib) = hv;
  *(uint4*)(WL + (size_t)r*N_INP + ib) = lv;
}

__global__ void k_prep_t2(const float* __restrict__ Wr, const float* __restrict__ Wo,
                          float* __restrict__ WRT, float* __restrict__ WoT) {
  int g = blockIdx.x*256 + threadIdx.x;
  if (g < N_HID*N_HID) {
    int j = g >> 9, r = g & 511;
    WRT[g] = Wr[r*N_HID + j];
  }
  if (g < N_HID*N_OUT) {
    int r = g / N_OUT, o = g - r*N_OUT;
    WoT[g] = Wo[o*N_HID + r];
  }
}
// NOTE: summation order of Srow/SOs is spike-determining — keep serial order exactly.
__global__ void k_prep_sums(const float* __restrict__ Wr, const float* __restrict__ Wo,
                            float* __restrict__ Srow, float* __restrict__ SOs,
                            int* __restrict__ tmax) {
  int g = blockIdx.x*256 + threadIdx.x;
  if (g < N_HID) {
    float s = 0.f;
    for (int j = 0; j < N_HID; ++j) s += Wr[g*N_HID + j];
    Srow[g] = s;
  } else if (g < N_HID + N_OUT) {
    int o = g - N_HID;
    float s = 0.f;
    for (int r = 0; r < N_HID; ++r) s += Wo[o*N_HID + r];
    SOs[o] = s;
  }
  if (g < BB) tmax[g] = 0;
}

// ---------------- phase A: INL = X @ (WH^T + WL^T), MFMA split-bf16 ----------------
__global__ __launch_bounds__(256) void k_gemm(const float* __restrict__ x,
                                              const unsigned short* __restrict__ WH,
                                              const unsigned short* __restrict__ WL,
                                              float* __restrict__ INL) {
  __shared__ __align__(16) unsigned short sA [128*32];
  __shared__ __align__(16) unsigned short sBh[128*32];
  __shared__ __align__(16) unsigned short sBl[128*32];
  const int tid = threadIdx.x, lane = tid & 63, w = tid >> 6;
  const int k0 = blockIdx.x * 128;
  const int c0 = blockIdx.y * 128;
  const int wr = w >> 1, wc = w & 1;
  const int fr = lane & 15, fk = lane >> 4;

  const int a_r  = tid >> 1;
  const int a_cb = (tid & 1) * 16;
  const int b_r  = tid >> 2;
  const int b_c  = (tid & 3) * 8;

  const float* xr = x + (size_t)(k0 + a_r) * N_IN;
  const unsigned short* gh = WH + (size_t)(c0 + b_r) * N_INP;
  const unsigned short* gl = WL + (size_t)(c0 + b_r) * N_INP;

  f32x4 acc[4][4];
  #pragma unroll
  for (int m = 0; m < 4; ++m)
    #pragma unroll
    for (int n = 0; n < 4; ++n)
      acc[m][n] = (f32x4){0.f, 0.f, 0.f, 0.f};

  for (int s = 0; s < N_INP/32; ++s) {
    const int i0 = s * 32;
    float av[16];
    const int col0 = i0 + a_cb;
    if (col0 + 16 <= N_IN) {
      float4 t0 = *(const float4*)(xr + col0);
      float4 t1 = *(const float4*)(xr + col0 + 4);
      float4 t2 = *(const float4*)(xr + col0 + 8);
      float4 t3 = *(const float4*)(xr + col0 + 12);
      av[0]=t0.x; av[1]=t0.y; av[2]=t0.z; av[3]=t0.w;
      av[4]=t1.x; av[5]=t1.y; av[6]=t1.z; av[7]=t1.w;
      av[8]=t2.x; av[9]=t2.y; av[10]=t2.z; av[11]=t2.w;
      av[12]=t3.x; av[13]=t3.y; av[14]=t3.z; av[15]=t3.w;
    } else {
      #pragma unroll
      for (int j = 0; j < 16; ++j) av[j] = (col0 + j < N_IN) ? xr[col0 + j] : 0.f;
    }
    uint32_t us[8];
    #pragma unroll
    for (int p = 0; p < 8; ++p) {
      uint32_t lo = __builtin_bit_cast(uint32_t, av[2*p])   >> 16;
      uint32_t hi = __builtin_bit_cast(uint32_t, av[2*p+1]) & 0xFFFF0000u;
      us[p] = hi | lo;
    }
    *(uint4*)&sA[a_r*32 + a_cb]     = make_uint4(us[0], us[1], us[2], us[3]);
    *(uint4*)&sA[a_r*32 + a_cb + 8] = make_uint4(us[4], us[5], us[6], us[7]);
    *(uint4*)&sBh[b_r*32 + b_c]      = *(const uint4*)(gh + i0 + b_c);
    *(uint4*)&sBh[(b_r+64)*32 + b_c] = *(const uint4*)(gh + (size_t)64*N_INP + i0 + b_c);
    *(uint4*)&sBl[b_r*32 + b_c]      = *(const uint4*)(gl + i0 + b_c);
    *(uint4*)&sBl[(b_r+64)*32 + b_c] = *(const uint4*)(gl + (size_t)64*N_INP + i0 + b_c);
    __syncthreads();

    bf16x8 a[4], bh[4], bl[4];
    #pragma unroll
    for (int m = 0; m < 4; ++m)
      a[m] = *(const bf16x8*)&sA[(wr*64 + m*16 + fr)*32 + fk*8];
    #pragma unroll
    for (int n = 0; n < 4; ++n) {
      bh[n] = *(const bf16x8*)&sBh[(wc*64 + n*16 + fr)*32 + fk*8];
      bl[n] = *(const bf16x8*)&sBl[(wc*64 + n*16 + fr)*32 + fk*8];
    }
    #pragma unroll
    for (int m = 0; m < 4; ++m)
      #pragma unroll
      for (int n = 0; n < 4; ++n) {
        acc[m][n] = __builtin_amdgcn_mfma_f32_16x16x32_bf16(a[m], bh[n], acc[m][n], 0, 0, 0);
        acc[m][n] = __builtin_amdgcn_mfma_f32_16x16x32_bf16(a[m], bl[n], acc[m][n], 0, 0, 0);
      }
    __syncthreads();
  }
  #pragma unroll
  for (int m = 0; m < 4; ++m) {
    #pragma unroll
    for (int n = 0; n < 4; ++n) {
      #pragma unroll
      for (int reg = 0; reg < 4; ++reg) {
        const int row = k0 + wr*64 + m*16 + (lane>>4)*4 + reg;
        const int col = c0 + wc*64 + n*16 + fr;
        INL[(size_t)row*N_HID + col] = acc[m][n][reg];
      }
    }
  }
}

// ---------------- phase B: one WAVE per batch row; LDS list for slow steps; in-scan go ----------------
// lane owns neurons r = j*64+lane (j=0..7); output neuron o = lane (lane<20).
__global__ __launch_bounds__(64) void k_scan(
    float* __restrict__ INL, const float* __restrict__ label,
    const float* __restrict__ WoT, const float* __restrict__ WRT,
    const float* __restrict__ Srow, const float* __restrict__ SOs,
    unsigned long long* __restrict__ hsbits, float* __restrict__ outs,
    float* __restrict__ errb, float* __restrict__ pgo)
{
  __shared__ int list[N_HID];                     // single wave: no barriers needed
  const int b = blockIdx.x, lane = threadIdx.x;
  const size_t base = (size_t)b*TT;
  float srw[8], hm[8], curv[8], nxtv[8], tout[8];
  int hs[8];
  float goA[8][N_OUT];
  #pragma unroll
  for (int j = 0; j < 8; ++j) {
    srw[j] = Srow[j*64 + lane]; hm[j] = 0.f; hs[j] = 0; tout[j] = 0.f;
    #pragma unroll
    for (int o = 0; o < N_OUT; ++o) goA[j][o] = 0.f;
  }
  #pragma unroll
  for (int j = 0; j < 8; ++j) curv[j] = INL[base*N_HID + j*64 + lane];
  #pragma unroll
  for (int j = 0; j < 8; ++j) nxtv[j] = INL[(base+1)*N_HID + j*64 + lane];
  const float SOsl = (lane < N_OUT) ? SOs[lane] : 0.f;
  float lab = (lane < N_OUT) ? label[base*N_OUT + lane] : 0.f;
  float om = 0.f; int osb = 0;
  int cnt_prev = 0, mode_prev = 0;

  for (int t = 0; t < TT; ++t) {
    const size_t k = base + t;
    // 2-deep prefetch of IN, 1-deep of label
    float nn[8];
    const size_t k2 = (t + 2 < TT) ? (k + 2) : (base + TT - 1);
    #pragma unroll
    for (int j = 0; j < 8; ++j) nn[j] = INL[k2*N_HID + j*64 + lane];
    const size_t k1 = (t + 1 < TT) ? (k + 1) : k;
    const float labn = (lane < N_OUT) ? label[k1*N_OUT + lane] : 0.f;

    // recurrent drive from prev-step list (wave-uniform control)
    float rec[8];
    if (cnt_prev == 0 && mode_prev == 1) {        // all spiked
      #pragma unroll
      for (int j = 0; j < 8; ++j) rec[j] = srw[j];
    } else if (cnt_prev == 0) {
      #pragma unroll
      for (int j = 0; j < 8; ++j) rec[j] = 0.f;
    } else {
      float racc[8];
      #pragma unroll
      for (int j = 0; j < 8; ++j) racc[j] = 0.f;
      for (int it = 0; it < cnt_prev; ++it) {
        const int jj = list[it];
        #pragma unroll
        for (int j = 0; j < 8; ++j) racc[j] += WRT[jj*N_HID + j*64 + lane];
      }
      #pragma unroll
      for (int j = 0; j < 8; ++j) rec[j] = mode_prev ? (srw[j] - racc[j]) : racc[j];
    }

    // hidden membrane + spikes
    float nhm[8]; int nhs[8]; unsigned long long m[8];
    #pragma unroll
    for (int j = 0; j < 8; ++j)
      nhm[j] = TAU*hm[j]*(hs[j] ? 0.f : 1.f) + curv[j] + rec[j];
    #pragma unroll
    for (int j = 0; j < 8; ++j) { nhs[j] = (nhm[j] >= THR) ? 1 : 0; m[j] = __ballot(nhs[j] != 0); }
    int pcs[8], ctot = 0;
    #pragma unroll
    for (int j = 0; j < 8; ++j) { pcs[j] = (int)__popcll(m[j]); ctot += pcs[j]; }
    if (lane == 0) {
      #pragma unroll
      for (int j = 0; j < 8; ++j) hsbits[k*8 + j] = m[j];
    }
    const int mode = (ctot <= 256) ? 0 : 1;
    const int cnt  = mode ? (512 - ctot) : ctot;  // cnt==0 && mode==1 -> all spiked

    // build list (slow steps only) — same compaction order as earlier rounds
    float drv;
    if (cnt != 0) {
      int pre[8];
      pre[0] = 0;
      #pragma unroll
      for (int q = 1; q < 8; ++q) pre[q] = pre[q-1] + (mode ? 64 - pcs[q-1] : pcs[q-1]);
      const unsigned long long below = (1ULL << lane) - 1ULL;
      #pragma unroll
      for (int q = 0; q < 8; ++q) {
        const unsigned long long sm = mode ? ~m[q] : m[q];
        if ((sm >> lane) & 1ULL)
          list[pre[q] + (int)__popcll(sm & below)] = q*64 + lane;
      }
      // output drive via WoT (lane < 20)
      float cdr = 0.f;
      for (int it = 0; it < cnt; ++it) {
        const int jj = list[it];
        cdr += (lane < N_OUT) ? WoT[jj*N_OUT + lane] : 0.f;
      }
      drv = mode ? (SOsl - cdr) : cdr;
    } else {
      drv = mode ? SOsl : 0.f;
    }

    // output neuron update (o = lane)
    om = TAU*om*(osb ? 0.f : 1.f) + drv;
    const int nos = (om >= THR) ? 1 : 0;
    float err = 0.f;
    if (lane < N_OUT) {
      const float osf = nos ? 1.f : 0.f;
      err = osf - lab;
      outs[k*N_OUT + lane] = osf;
      errb[k*N_OUT + lane] = err;
    }
    osb = nos;

    // tout + go accumulation (same FP order per (o,r) as rounds 4-7)
    #pragma unroll
    for (int j = 0; j < 8; ++j) tout[j] = TAU_O*tout[j] + (nhs[j] ? 1.f : 0.f);
    #pragma unroll
    for (int o = 0; o < N_OUT; ++o) {
      const float e_o = __shfl(err, o);
      #pragma unroll
      for (int j = 0; j < 8; ++j) goA[j][o] += e_o * tout[j];
    }

    // h' store (in place over IN)
    #pragma unroll
    for (int j = 0; j < 8; ++j) {
      const float a  = fabsf(nhm[j] - THR) / THR;
      const float ht = GAM * fmaxf(0.f, 1.f - a);
      INL[k*N_HID + j*64 + lane] = ht;
      hm[j] = nhm[j]; hs[j] = nhs[j];
    }
    #pragma unroll
    for (int j = 0; j < 8; ++j) { curv[j] = nxtv[j]; nxtv[j] = nn[j]; }
    cnt_prev = cnt; mode_prev = mode;
    lab = labn;
  }
  #pragma unroll
  for (int o = 0; o < N_OUT; ++o)
    #pragma unroll
    for (int j = 0; j < 8; ++j)
      pgo[((size_t)b*N_OUT + o)*N_HID + j*64 + lane] = goA[j][o];
}

// ---------------- phase C: fused L = (err@Wo)*h' and reverse filter M, in place ----------------
__global__ __launch_bounds__(256) void k_mfilter(float* __restrict__ INL,
                                                 const float* __restrict__ errb,
                                                 const float* __restrict__ Wo,
                                                 int* __restrict__ tmax) {
  const int g = blockIdx.x*256 + threadIdx.x;      // (b, r)
  const int b = g >> 9, r = g & 511;
  float woc[N_OUT];
  #pragma unroll
  for (int o = 0; o < N_OUT; ++o) woc[o] = Wo[o*N_HID + r];
  const size_t rb = (size_t)b*TT;
  float mval = 0.f; int last = -1;
  float hcur = INL[(rb + TT - 1)*N_HID + r];
  for (int t = TT - 1; t >= 0; --t) {
    const float hnxt = (t > 0) ? INL[(rb + t - 1)*N_HID + r] : 0.f;
    float d = 0.f;
    #pragma unroll
    for (int o = 0; o < N_OUT; ++o) d += errb[(rb + t)*N_OUT + o] * woc[o];
    const float v = d*hcur + TAU*mval;
    INL[(rb + t)*N_HID + r] = v;
    mval = v;
    if (v != 0.f && last < 0) last = t;
    hcur = hnxt;
  }
  if (last >= 0) atomicMax(tmax + b, last + 1);
}

// ---------------- phase D: go = 0.1 * sum_b pgo[b]  (160 blocks, 4-way b-split, ordered reduce) ----------------
__global__ __launch_bounds__(256) void k_go(const float* __restrict__ pgo, float* __restrict__ go) {
  __shared__ float red[4][64];
  const int l = threadIdx.x & 63;
  const int ch = threadIdx.x >> 6;
  const int col = blockIdx.x*64 + l;
  float s = 0.f;
  for (int b2 = ch*64; b2 < ch*64 + 64; ++b2)
    s += pgo[(size_t)b2*(N_OUT*N_HID) + col];
  red[ch][l] = s;
  __syncthreads();
  if (ch == 0) go[col] = 0.1f*(((red[0][l] + red[1][l]) + red[2][l]) + red[3][l]);
}

// ---------------- phase D: gf partials over b-chunks ----------------
__global__ __launch_bounds__(256) void k_gf(const float* __restrict__ M, const float* __restrict__ x,
                                            const int* __restrict__ tmax,
                                            float* __restrict__ gfp) {
  const int lane = threadIdx.x & 63, w = threadIdx.x >> 6;
  const int r  = blockIdx.x*64 + lane;
  const int i0 = blockIdx.y*64 + w*16;
  const int ch = blockIdx.z;
  const int b_lo = ch * (BB/NCH);
  __shared__ int cnt_sh[BB/NCH];
  if (threadIdx.x < BB/NCH) cnt_sh[threadIdx.x] = tmax[b_lo + threadIdx.x];
  __syncthreads();
  float acc[16];
  #pragma unroll
  for (int ii = 0; ii < 16; ++ii) acc[ii] = 0.f;
  int xi = i0 + (lane & 15); if (xi > N_IN - 1) xi = N_IN - 1;
  for (int bi = 0; bi < BB/NCH; ++bi) {
    const int ct = cnt_sh[bi];
    if (ct == 0) continue;
    const size_t kb = (size_t)(b_lo + bi)*TT;
    float mv = M[kb*N_HID + r];
    float xv = x[kb*N_IN + xi];
    for (int t = 0; t < ct; ++t) {
      float mv_n = 0.f, xv_n = 0.f;
      if (t + 1 < ct) {
        mv_n = M[(kb + t + 1)*N_HID + r];
        xv_n = x[(kb + t + 1)*N_IN + xi];
      }
      #pragma unroll
      for (int ii = 0; ii < 16; ++ii) acc[ii] += mv * __shfl(xv, ii);
      mv = mv_n; xv = xv_n;
    }
  }
  #pragma unroll
  for (int ii = 0; ii < 16; ++ii) {
    const int i = i0 + ii;
    if (i < N_IN) gfp[(size_t)ch*(N_HID*N_IN) + (size_t)r*N_IN + i] = acc[ii];
  }
}

// ---------------- phase D: gr partials over b-chunks ----------------
__global__ __launch_bounds__(256) void k_gr(const float* __restrict__ M,
                                            const unsigned long long* __restrict__ hsbits,
                                            const int* __restrict__ tmax,
                                            float* __restrict__ grp) {
  const int lane = threadIdx.x & 63, w = threadIdx.x >> 6;
  const int r  = blockIdx.x*64 + lane;
  const int h0 = blockIdx.y*64 + w*16;
  const int ch = blockIdx.z;
  const int b_lo = ch * (BB/NCH);
  __shared__ int cnt_sh[BB/NCH];
  if (threadIdx.x < BB/NCH) cnt_sh[threadIdx.x] = tmax[b_lo + threadIdx.x];
  __syncthreads();
  float acc[16];
  #pragma unroll
  for (int ii = 0; ii < 16; ++ii) acc[ii] = 0.f;
  const int hw = h0 >> 6, sh = h0 & 63;
  for (int bi = 0; bi < BB/NCH; ++bi) {
    const int ct = cnt_sh[bi];
    if (ct == 0) continue;
    const size_t kb = (size_t)(b_lo + bi)*TT;
    float mv = M[kb*N_HID + r];
    unsigned long long word = hsbits[kb*8 + hw];
    for (int t = 0; t < ct; ++t) {
      float mv_n = 0.f; unsigned long long word_n = 0ULL;
      if (t + 1 < ct) {
        mv_n = M[(kb + t + 1)*N_HID + r];
        word_n = hsbits[(kb + t + 1)*8 + hw];
      }
      #pragma unroll
      for (int ii = 0; ii < 16; ++ii)
        if ((word >> (sh + ii)) & 1ULL) acc[ii] += mv;
      mv = mv_n; word = word_n;
    }
  }
  #pragma unroll
  for (int ii = 0; ii < 16; ++ii)
    grp[(size_t)ch*(N_HID*N_HID) + (size_t)r*N_HID + h0 + ii] = acc[ii];
}

// ---------------- phase D: deterministic partial reductions ----------------
__global__ void k_gfred(const float* __restrict__ gfp, float* __restrict__ gf) {
  const int g = blockIdx.x*256 + threadIdx.x;
  if (g < N_HID*N_IN) {
    float s = 0.f;
    #pragma unroll
    for (int c = 0; c < NCH; ++c) s += gfp[(size_t)c*(N_HID*N_IN) + g];
    gf[g] = 0.1f*s;
  }
}
__global__ void k_grred(const float* __restrict__ grp, float* __restrict__ gr) {
  const int g = blockIdx.x*256 + threadIdx.x;
  if (g < N_HID*N_HID) {
    float s = 0.f;
    #pragma unroll
    for (int c = 0; c < NCH; ++c) s += grp[(size_t)c*(N_HID*N_HID) + g];
    gr[g] = 0.1f*s;
  }
}

extern "C" void kernel_launch(void* const* d_in, const int* in_sizes, int n_in,
                              void* d_out, int out_size, void* d_ws, size_t ws_size,
                              hipStream_t stream) {
  const float* x     = (const float*)d_in[0];
  const float* label = (const float*)d_in[1];
  const float* W1    = (const float*)d_in[2];
  const float* Wr    = (const float*)d_in[3];
  const float* Wo    = (const float*)d_in[4];

  float* out  = (float*)d_out;
  float* outs = out;                                    // [256][100][20]
  float* gf   = out + 512000;                           // [512][700]
  float* gr   = out + 512000 + 358400;                  // [512][512]
  float* go   = out + 512000 + 358400 + 262144;         // [20][512]

  char* ws = (char*)d_ws;
  size_t off = 0;
  auto alloc = [&](size_t bytes) -> char* {
    char* p = ws + off;
    off += (bytes + 255) & ~(size_t)255;
    return p;
  };
  float* INL = (float*)alloc((size_t)NK*N_HID*sizeof(float));                    // 52.43 MB
  unsigned long long* hsb = (unsigned long long*)alloc((size_t)NK*8*sizeof(unsigned long long)); // 1.64 MB
  int* tmax = (int*)alloc((size_t)BB*sizeof(int));
  char* uni = alloc((size_t)20971520);                                           // 20 MB union region

  // early residents of uni (all dead before k_gf):
  unsigned short* WH = (unsigned short*)(uni);          // 0.72 MB  (dead after gemm)
  unsigned short* WL = (unsigned short*)(uni + 720896); // 0.72 MB  (dead after gemm)
  float* WRT  = (float*)(uni + 1441792);                // 1.05 MB  (dead after scan)
  float* Srow = (float*)(uni + 2490368);
  float* SOs  = (float*)(uni + 2492416);
  float* WoT  = (float*)(uni + 2494464);                // 40 KB    (dead after scan)
  float* errb = (float*)(uni + 2536448);                // 2.05 MB  (scan -> mfilter)
  float* pgo  = (float*)(uni + 4587520);                // 10.49 MB (scan -> k_go)
  // late residents:
  float* gfp  = (float*)(uni);                          // 11.47 MB (k_gf)
  float* grp  = (float*)(uni + 11468800);               // 8.39 MB  (k_gr)

  k_wsplit<<<(N_HID*88 + 255)/256, 256, 0, stream>>>(W1, WH, WL);
  k_prep_t2<<<(N_HID*N_HID + 255)/256, 256, 0, stream>>>(Wr, Wo, WRT, WoT);
  k_prep_sums<<<(N_HID + N_OUT + 255)/256, 256, 0, stream>>>(Wr, Wo, Srow, SOs, tmax);
  dim3 gg(NK/128, N_HID/128);
  k_gemm<<<gg, 256, 0, stream>>>(x, WH, WL, INL);
  k_scan<<<BB, 64, 0, stream>>>(INL, label, WoT, WRT, Srow, SOs, hsb, outs, errb, pgo);
  k_mfilter<<<(BB*N_HID)/256, 256, 0, stream>>>(INL, errb, Wo, tmax);
  k_go<<<(N_OUT*N_HID)/64, 256, 0, stream>>>(pgo, go);
  dim3 ggf(8, 11, NCH); k_gf<<<ggf, 256, 0, stream>>>(INL, x, tmax, gfp);
  dim3 ggr(8, 8, NCH);  k_gr<<<ggr, 256, 0, stream>>>(INL, hsb, tmax, grp);
  k_gfred<<<(N_HID*N_IN + 255)/256, 256, 0, stream>>>(gfp, gf);
  k_grred<<<(N_HID*N_HID + 255)/256, 256, 0, stream>>>(grp, gr);
}

// Round 10
// 516.191 us; speedup vs baseline: 1.4456x; 1.1169x over previous
//
#include <hip/hip_runtime.h>
#include <cstdint>
#include <cstddef>

#define N_IN  700
#define N_INP 704           // K padded to 32
#define N_HID 512
#define N_OUT 20
#define BB    256
#define TT    100
#define NK    (BB*TT)       // 25600
#define NCH   8             // split-k chunks for gf/gr

__device__ __constant__ const float TAU   = 0.6f;
__device__ __constant__ const float TAU_O = 0.6f;
__device__ __constant__ const float THR   = 0.6f;
__device__ __constant__ const float GAM   = 0.3f;

typedef float f32x4 __attribute__((ext_vector_type(4)));
typedef __bf16 bf16x8 __attribute__((ext_vector_type(8)));

__device__ __forceinline__ unsigned short f2bf_rne(float f) {
  uint32_t b = __builtin_bit_cast(uint32_t, f);
  uint32_t r = (b + 0x7FFFu + ((b >> 16) & 1u)) >> 16;
  return (unsigned short)r;
}
__device__ __forceinline__ float bf2f(unsigned short u) {
  uint32_t b = ((uint32_t)u) << 16;
  return __builtin_bit_cast(float, b);
}

// ---------------- prep: W split into hi+lo bf16, [r][i] layout padded to 704 ----------------
__global__ void k_wsplit(const float* __restrict__ W1,
                         unsigned short* __restrict__ WH,
                         unsigned short* __restrict__ WL) {
  int g = blockIdx.x*256 + threadIdx.x;
  if (g >= N_HID*88) return;
  int r = g / 88, c = g - (g/88)*88;
  int ib = c*8;
  unsigned short h[8], l[8];
  #pragma unroll
  for (int j = 0; j < 8; ++j) {
    int i = ib + j;
    float v = (i < N_IN) ? W1[r*N_IN + i] : 0.f;
    unsigned short hh = f2bf_rne(v);
    float res = v - bf2f(hh);
    h[j] = hh;
    l[j] = f2bf_rne(res);
  }
  uint4 hv = make_uint4((uint32_t)h[0] | ((uint32_t)h[1]<<16), (uint32_t)h[2] | ((uint32_t)h[3]<<16),
                        (uint32_t)h[4] | ((uint32_t)h[5]<<16), (uint32_t)h[6] | ((uint32_t)h[7]<<16));
  uint4 lv = make_uint4((uint32_t)l[0] | ((uint32_t)l[1]<<16), (uint32_t)l[2] | ((uint32_t)l[3]<<16),
                        (uint32_t)l[4] | ((uint32_t)l[5]<<16), (uint32_t)l[6] | ((uint32_t)l[7]<<16));
  *(uint4*)(WH + (size_t)r*N_INP + ib) = hv;
  *(uint4*)(WL + (size_t)r*N_INP + ib) = lv;
}

__global__ void k_prep_t2(const float* __restrict__ Wr, const float* __restrict__ Wo,
                          float* __restrict__ WRT, float* __restrict__ WoT) {
  int g = blockIdx.x*256 + threadIdx.x;
  if (g < N_HID*N_HID) {
    int j = g >> 9, r = g & 511;
    WRT[g] = Wr[r*N_HID + j];
  }
  if (g < N_HID*N_OUT) {
    int r = g / N_OUT, o = g - r*N_OUT;
    WoT[g] = Wo[o*N_HID + r];
  }
}
// NOTE: summation order of Srow/SOs is spike-determining — keep serial order exactly.
__global__ void k_prep_sums(const float* __restrict__ Wr, const float* __restrict__ Wo,
                            float* __restrict__ Srow, float* __restrict__ SOs,
                            int* __restrict__ tmax) {
  int g = blockIdx.x*256 + threadIdx.x;
  if (g < N_HID) {
    float s = 0.f;
    for (int j = 0; j < N_HID; ++j) s += Wr[g*N_HID + j];
    Srow[g] = s;
  } else if (g < N_HID + N_OUT) {
    int o = g - N_HID;
    float s = 0.f;
    for (int r = 0; r < N_HID; ++r) s += Wo[o*N_HID + r];
    SOs[o] = s;
  }
  if (g < BB) tmax[g] = 0;
}

// ---------------- phase A: INL = X @ (WH^T + WL^T), MFMA split-bf16 ----------------
__global__ __launch_bounds__(256) void k_gemm(const float* __restrict__ x,
                                              const unsigned short* __restrict__ WH,
                                              const unsigned short* __restrict__ WL,
                                              float* __restrict__ INL) {
  __shared__ __align__(16) unsigned short sA [128*32];
  __shared__ __align__(16) unsigned short sBh[128*32];
  __shared__ __align__(16) unsigned short sBl[128*32];
  const int tid = threadIdx.x, lane = tid & 63, w = tid >> 6;
  const int k0 = blockIdx.x * 128;
  const int c0 = blockIdx.y * 128;
  const int wr = w >> 1, wc = w & 1;
  const int fr = lane & 15, fk = lane >> 4;

  const int a_r  = tid >> 1;
  const int a_cb = (tid & 1) * 16;
  const int b_r  = tid >> 2;
  const int b_c  = (tid & 3) * 8;

  const float* xr = x + (size_t)(k0 + a_r) * N_IN;
  const unsigned short* gh = WH + (size_t)(c0 + b_r) * N_INP;
  const unsigned short* gl = WL + (size_t)(c0 + b_r) * N_INP;

  f32x4 acc[4][4];
  #pragma unroll
  for (int m = 0; m < 4; ++m)
    #pragma unroll
    for (int n = 0; n < 4; ++n)
      acc[m][n] = (f32x4){0.f, 0.f, 0.f, 0.f};

  for (int s = 0; s < N_INP/32; ++s) {
    const int i0 = s * 32;
    float av[16];
    const int col0 = i0 + a_cb;
    if (col0 + 16 <= N_IN) {
      float4 t0 = *(const float4*)(xr + col0);
      float4 t1 = *(const float4*)(xr + col0 + 4);
      float4 t2 = *(const float4*)(xr + col0 + 8);
      float4 t3 = *(const float4*)(xr + col0 + 12);
      av[0]=t0.x; av[1]=t0.y; av[2]=t0.z; av[3]=t0.w;
      av[4]=t1.x; av[5]=t1.y; av[6]=t1.z; av[7]=t1.w;
      av[8]=t2.x; av[9]=t2.y; av[10]=t2.z; av[11]=t2.w;
      av[12]=t3.x; av[13]=t3.y; av[14]=t3.z; av[15]=t3.w;
    } else {
      #pragma unroll
      for (int j = 0; j < 16; ++j) av[j] = (col0 + j < N_IN) ? xr[col0 + j] : 0.f;
    }
    uint32_t us[8];
    #pragma unroll
    for (int p = 0; p < 8; ++p) {
      uint32_t lo = __builtin_bit_cast(uint32_t, av[2*p])   >> 16;
      uint32_t hi = __builtin_bit_cast(uint32_t, av[2*p+1]) & 0xFFFF0000u;
      us[p] = hi | lo;
    }
    *(uint4*)&sA[a_r*32 + a_cb]     = make_uint4(us[0], us[1], us[2], us[3]);
    *(uint4*)&sA[a_r*32 + a_cb + 8] = make_uint4(us[4], us[5], us[6], us[7]);
    *(uint4*)&sBh[b_r*32 + b_c]      = *(const uint4*)(gh + i0 + b_c);
    *(uint4*)&sBh[(b_r+64)*32 + b_c] = *(const uint4*)(gh + (size_t)64*N_INP + i0 + b_c);
    *(uint4*)&sBl[b_r*32 + b_c]      = *(const uint4*)(gl + i0 + b_c);
    *(uint4*)&sBl[(b_r+64)*32 + b_c] = *(const uint4*)(gl + (size_t)64*N_INP + i0 + b_c);
    __syncthreads();

    bf16x8 a[4], bh[4], bl[4];
    #pragma unroll
    for (int m = 0; m < 4; ++m)
      a[m] = *(const bf16x8*)&sA[(wr*64 + m*16 + fr)*32 + fk*8];
    #pragma unroll
    for (int n = 0; n < 4; ++n) {
      bh[n] = *(const bf16x8*)&sBh[(wc*64 + n*16 + fr)*32 + fk*8];
      bl[n] = *(const bf16x8*)&sBl[(wc*64 + n*16 + fr)*32 + fk*8];
    }
    #pragma unroll
    for (int m = 0; m < 4; ++m)
      #pragma unroll
      for (int n = 0; n < 4; ++n) {
        acc[m][n] = __builtin_amdgcn_mfma_f32_16x16x32_bf16(a[m], bh[n], acc[m][n], 0, 0, 0);
        acc[m][n] = __builtin_amdgcn_mfma_f32_16x16x32_bf16(a[m], bl[n], acc[m][n], 0, 0, 0);
      }
    __syncthreads();
  }
  #pragma unroll
  for (int m = 0; m < 4; ++m) {
    #pragma unroll
    for (int n = 0; n < 4; ++n) {
      #pragma unroll
      for (int reg = 0; reg < 4; ++reg) {
        const int row = k0 + wr*64 + m*16 + (lane>>4)*4 + reg;
        const int col = c0 + wc*64 + n*16 + fr;
        INL[(size_t)row*N_HID + col] = acc[m][n][reg];
      }
    }
  }
}

// ---------------- phase B: one WAVE per batch row; no go-accum (reg budget!) ----------------
// lane owns neurons r = j*64+lane (j=0..7); output neuron o = lane (lane<20).
__global__ __launch_bounds__(64, 1) void k_scan(
    float* __restrict__ INL, const float* __restrict__ label,
    const float* __restrict__ WoT, const float* __restrict__ WRT,
    const float* __restrict__ Srow, const float* __restrict__ SOs,
    unsigned long long* __restrict__ hsbits, float* __restrict__ outs,
    float* __restrict__ errb)
{
  __shared__ int list[N_HID];                     // single wave: no barriers needed
  const int b = blockIdx.x, lane = threadIdx.x;
  const size_t base = (size_t)b*TT;
  float srw[8], hm[8], curv[8], nxtv[8];
  int hs[8];
  #pragma unroll
  for (int j = 0; j < 8; ++j) { srw[j] = Srow[j*64 + lane]; hm[j] = 0.f; hs[j] = 0; }
  #pragma unroll
  for (int j = 0; j < 8; ++j) curv[j] = INL[base*N_HID + j*64 + lane];
  #pragma unroll
  for (int j = 0; j < 8; ++j) nxtv[j] = INL[(base+1)*N_HID + j*64 + lane];
  const float SOsl = (lane < N_OUT) ? SOs[lane] : 0.f;
  float lab = (lane < N_OUT) ? label[base*N_OUT + lane] : 0.f;
  float om = 0.f; int osb = 0;
  int cnt_prev = 0, mode_prev = 0;

  for (int t = 0; t < TT; ++t) {
    const size_t k = base + t;
    // 2-deep prefetch of IN, 1-deep of label
    float nn[8];
    const size_t k2 = (t + 2 < TT) ? (k + 2) : (base + TT - 1);
    #pragma unroll
    for (int j = 0; j < 8; ++j) nn[j] = INL[k2*N_HID + j*64 + lane];
    const size_t k1 = (t + 1 < TT) ? (k + 1) : k;
    const float labn = (lane < N_OUT) ? label[k1*N_OUT + lane] : 0.f;

    // recurrent drive from prev-step list (wave-uniform control)
    float rec[8];
    if (cnt_prev == 0 && mode_prev == 1) {        // all spiked
      #pragma unroll
      for (int j = 0; j < 8; ++j) rec[j] = srw[j];
    } else if (cnt_prev == 0) {
      #pragma unroll
      for (int j = 0; j < 8; ++j) rec[j] = 0.f;
    } else {
      float racc[8];
      #pragma unroll
      for (int j = 0; j < 8; ++j) racc[j] = 0.f;
      for (int it = 0; it < cnt_prev; ++it) {
        const int jj = list[it];
        #pragma unroll
        for (int j = 0; j < 8; ++j) racc[j] += WRT[jj*N_HID + j*64 + lane];
      }
      #pragma unroll
      for (int j = 0; j < 8; ++j) rec[j] = mode_prev ? (srw[j] - racc[j]) : racc[j];
    }

    // hidden membrane + spikes
    float nhm[8]; int nhs[8]; unsigned long long m[8];
    #pragma unroll
    for (int j = 0; j < 8; ++j)
      nhm[j] = TAU*hm[j]*(hs[j] ? 0.f : 1.f) + curv[j] + rec[j];
    #pragma unroll
    for (int j = 0; j < 8; ++j) { nhs[j] = (nhm[j] >= THR) ? 1 : 0; m[j] = __ballot(nhs[j] != 0); }
    int pcs[8], ctot = 0;
    #pragma unroll
    for (int j = 0; j < 8; ++j) { pcs[j] = (int)__popcll(m[j]); ctot += pcs[j]; }
    if (lane == 0) {
      #pragma unroll
      for (int j = 0; j < 8; ++j) hsbits[k*8 + j] = m[j];
    }
    const int mode = (ctot <= 256) ? 0 : 1;
    const int cnt  = mode ? (512 - ctot) : ctot;  // cnt==0 && mode==1 -> all spiked

    // build list (slow steps only) — same compaction order as earlier rounds
    float drv;
    if (cnt != 0) {
      int pre[8];
      pre[0] = 0;
      #pragma unroll
      for (int q = 1; q < 8; ++q) pre[q] = pre[q-1] + (mode ? 64 - pcs[q-1] : pcs[q-1]);
      const unsigned long long below = (1ULL << lane) - 1ULL;
      #pragma unroll
      for (int q = 0; q < 8; ++q) {
        const unsigned long long sm = mode ? ~m[q] : m[q];
        if ((sm >> lane) & 1ULL)
          list[pre[q] + (int)__popcll(sm & below)] = q*64 + lane;
      }
      // output drive via WoT (lane < 20)
      float cdr = 0.f;
      for (int it = 0; it < cnt; ++it) {
        const int jj = list[it];
        cdr += (lane < N_OUT) ? WoT[jj*N_OUT + lane] : 0.f;
      }
      drv = mode ? (SOsl - cdr) : cdr;
    } else {
      drv = mode ? SOsl : 0.f;
    }

    // output neuron update (o = lane)
    om = TAU*om*(osb ? 0.f : 1.f) + drv;
    const int nos = (om >= THR) ? 1 : 0;
    if (lane < N_OUT) {
      const float osf = nos ? 1.f : 0.f;
      outs[k*N_OUT + lane] = osf;
      errb[k*N_OUT + lane] = osf - lab;
    }
    osb = nos;

    // h' store (in place over IN)
    #pragma unroll
    for (int j = 0; j < 8; ++j) {
      const float a  = fabsf(nhm[j] - THR) / THR;
      const float ht = GAM * fmaxf(0.f, 1.f - a);
      INL[k*N_HID + j*64 + lane] = ht;
      hm[j] = nhm[j]; hs[j] = nhs[j];
    }
    #pragma unroll
    for (int j = 0; j < 8; ++j) { curv[j] = nxtv[j]; nxtv[j] = nn[j]; }
    cnt_prev = cnt; mode_prev = mode;
    lab = labn;
  }
}

// ---------------- phase C: fused L->M reverse filter + go accumulation (F-filter identity) ----------------
// go[o][r] = sum_t spike[t,r] * F[t,o],  F[t] = err[t] + TAU_O*F[t+1]  (backward, matches loop)
__global__ __launch_bounds__(256) void k_mfilter(float* __restrict__ INL,
                                                 const float* __restrict__ errb,
                                                 const unsigned long long* __restrict__ hsbits,
                                                 const float* __restrict__ Wo,
                                                 int* __restrict__ tmax,
                                                 float* __restrict__ pgo) {
  const int g = blockIdx.x*256 + threadIdx.x;      // (b, r)
  const int b = g >> 9, r = g & 511;
  const int hw = r >> 6, sh = r & 63;
  float woc[N_OUT], F[N_OUT], goacc[N_OUT];
  #pragma unroll
  for (int o = 0; o < N_OUT; ++o) { woc[o] = Wo[o*N_HID + r]; F[o] = 0.f; goacc[o] = 0.f; }
  const size_t rb = (size_t)b*TT;
  float mval = 0.f; int last = -1;
  float hcur = INL[(rb + TT - 1)*N_HID + r];
  for (int t = TT - 1; t >= 0; --t) {
    const float hnxt = (t > 0) ? INL[(rb + t - 1)*N_HID + r] : 0.f;
    const unsigned long long word = hsbits[(rb + t)*8 + hw];
    float ev[N_OUT];
    #pragma unroll
    for (int o = 0; o < N_OUT; ++o) ev[o] = errb[(rb + t)*N_OUT + o];
    float d = 0.f;
    #pragma unroll
    for (int o = 0; o < N_OUT; ++o) d += ev[o] * woc[o];
    #pragma unroll
    for (int o = 0; o < N_OUT; ++o) F[o] = ev[o] + TAU_O*F[o];
    if ((word >> sh) & 1ULL) {
      #pragma unroll
      for (int o = 0; o < N_OUT; ++o) goacc[o] += F[o];
    }
    const float v = d*hcur + TAU*mval;
    INL[(rb + t)*N_HID + r] = v;
    mval = v;
    if (v != 0.f && last < 0) last = t;
    hcur = hnxt;
  }
  if (last >= 0) atomicMax(tmax + b, last + 1);
  #pragma unroll
  for (int o = 0; o < N_OUT; ++o)
    pgo[((size_t)b*N_OUT + o)*N_HID + r] = goacc[o];
}

// ---------------- phase D: go = 0.1 * sum_b pgo[b]  (160 blocks, 4-way b-split, ordered reduce) ----------------
__global__ __launch_bounds__(256) void k_go(const float* __restrict__ pgo, float* __restrict__ go) {
  __shared__ float red[4][64];
  const int l = threadIdx.x & 63;
  const int ch = threadIdx.x >> 6;
  const int col = blockIdx.x*64 + l;
  float s = 0.f;
  for (int b2 = ch*64; b2 < ch*64 + 64; ++b2)
    s += pgo[(size_t)b2*(N_OUT*N_HID) + col];
  red[ch][l] = s;
  __syncthreads();
  if (ch == 0) go[col] = 0.1f*(((red[0][l] + red[1][l]) + red[2][l]) + red[3][l]);
}

// ---------------- phase D: gf partials over b-chunks ----------------
__global__ __launch_bounds__(256) void k_gf(const float* __restrict__ M, const float* __restrict__ x,
                                            const int* __restrict__ tmax,
                                            float* __restrict__ gfp) {
  const int lane = threadIdx.x & 63, w = threadIdx.x >> 6;
  const int r  = blockIdx.x*64 + lane;
  const int i0 = blockIdx.y*64 + w*16;
  const int ch = blockIdx.z;
  const int b_lo = ch * (BB/NCH);
  __shared__ int cnt_sh[BB/NCH];
  if (threadIdx.x < BB/NCH) cnt_sh[threadIdx.x] = tmax[b_lo + threadIdx.x];
  __syncthreads();
  float acc[16];
  #pragma unroll
  for (int ii = 0; ii < 16; ++ii) acc[ii] = 0.f;
  int xi = i0 + (lane & 15); if (xi > N_IN - 1) xi = N_IN - 1;
  for (int bi = 0; bi < BB/NCH; ++bi) {
    const int ct = cnt_sh[bi];
    if (ct == 0) continue;
    const size_t kb = (size_t)(b_lo + bi)*TT;
    float mv = M[kb*N_HID + r];
    float xv = x[kb*N_IN + xi];
    for (int t = 0; t < ct; ++t) {
      float mv_n = 0.f, xv_n = 0.f;
      if (t + 1 < ct) {
        mv_n = M[(kb + t + 1)*N_HID + r];
        xv_n = x[(kb + t + 1)*N_IN + xi];
      }
      #pragma unroll
      for (int ii = 0; ii < 16; ++ii) acc[ii] += mv * __shfl(xv, ii);
      mv = mv_n; xv = xv_n;
    }
  }
  #pragma unroll
  for (int ii = 0; ii < 16; ++ii) {
    const int i = i0 + ii;
    if (i < N_IN) gfp[(size_t)ch*(N_HID*N_IN) + (size_t)r*N_IN + i] = acc[ii];
  }
}

// ---------------- phase D: gr partials over b-chunks ----------------
__global__ __launch_bounds__(256) void k_gr(const float* __restrict__ M,
                                            const unsigned long long* __restrict__ hsbits,
                                            const int* __restrict__ tmax,
                                            float* __restrict__ grp) {
  const int lane = threadIdx.x & 63, w = threadIdx.x >> 6;
  const int r  = blockIdx.x*64 + lane;
  const int h0 = blockIdx.y*64 + w*16;
  const int ch = blockIdx.z;
  const int b_lo = ch * (BB/NCH);
  __shared__ int cnt_sh[BB/NCH];
  if (threadIdx.x < BB/NCH) cnt_sh[threadIdx.x] = tmax[b_lo + threadIdx.x];
  __syncthreads();
  float acc[16];
  #pragma unroll
  for (int ii = 0; ii < 16; ++ii) acc[ii] = 0.f;
  const int hw = h0 >> 6, sh = h0 & 63;
  for (int bi = 0; bi < BB/NCH; ++bi) {
    const int ct = cnt_sh[bi];
    if (ct == 0) continue;
    const size_t kb = (size_t)(b_lo + bi)*TT;
    float mv = M[kb*N_HID + r];
    unsigned long long word = hsbits[kb*8 + hw];
    for (int t = 0; t < ct; ++t) {
      float mv_n = 0.f; unsigned long long word_n = 0ULL;
      if (t + 1 < ct) {
        mv_n = M[(kb + t + 1)*N_HID + r];
        word_n = hsbits[(kb + t + 1)*8 + hw];
      }
      #pragma unroll
      for (int ii = 0; ii < 16; ++ii)
        if ((word >> (sh + ii)) & 1ULL) acc[ii] += mv;
      mv = mv_n; word = word_n;
    }
  }
  #pragma unroll
  for (int ii = 0; ii < 16; ++ii)
    grp[(size_t)ch*(N_HID*N_HID) + (size_t)r*N_HID + h0 + ii] = acc[ii];
}

// ---------------- phase D: deterministic partial reductions ----------------
__global__ void k_gfred(const float* __restrict__ gfp, float* __restrict__ gf) {
  const int g = blockIdx.x*256 + threadIdx.x;
  if (g < N_HID*N_IN) {
    float s = 0.f;
    #pragma unroll
    for (int c = 0; c < NCH; ++c) s += gfp[(size_t)c*(N_HID*N_IN) + g];
    gf[g] = 0.1f*s;
  }
}
__global__ void k_grred(const float* __restrict__ grp, float* __restrict__ gr) {
  const int g = blockIdx.x*256 + threadIdx.x;
  if (g < N_HID*N_HID) {
    float s = 0.f;
    #pragma unroll
    for (int c = 0; c < NCH; ++c) s += grp[(size_t)c*(N_HID*N_HID) + g];
    gr[g] = 0.1f*s;
  }
}

extern "C" void kernel_launch(void* const* d_in, const int* in_sizes, int n_in,
                              void* d_out, int out_size, void* d_ws, size_t ws_size,
                              hipStream_t stream) {
  const float* x     = (const float*)d_in[0];
  const float* label = (const float*)d_in[1];
  const float* W1    = (const float*)d_in[2];
  const float* Wr    = (const float*)d_in[3];
  const float* Wo    = (const float*)d_in[4];

  float* out  = (float*)d_out;
  float* outs = out;                                    // [256][100][20]
  float* gf   = out + 512000;                           // [512][700]
  float* gr   = out + 512000 + 358400;                  // [512][512]
  float* go   = out + 512000 + 358400 + 262144;         // [20][512]

  char* ws = (char*)d_ws;
  size_t off = 0;
  auto alloc = [&](size_t bytes) -> char* {
    char* p = ws + off;
    off += (bytes + 255) & ~(size_t)255;
    return p;
  };
  float* INL = (float*)alloc((size_t)NK*N_HID*sizeof(float));                    // 52.43 MB
  unsigned long long* hsb = (unsigned long long*)alloc((size_t)NK*8*sizeof(unsigned long long)); // 1.64 MB
  int* tmax = (int*)alloc((size_t)BB*sizeof(int));
  char* uni = alloc((size_t)20971520);                                           // 20 MB union region

  // early residents of uni (all dead before k_gf):
  unsigned short* WH = (unsigned short*)(uni);          // 0.72 MB  (dead after gemm)
  unsigned short* WL = (unsigned short*)(uni + 720896); // 0.72 MB  (dead after gemm)
  float* WRT  = (float*)(uni + 1441792);                // 1.05 MB  (dead after scan)
  float* Srow = (float*)(uni + 2490368);
  float* SOs  = (float*)(uni + 2492416);
  float* WoT  = (float*)(uni + 2494464);                // 40 KB    (dead after scan)
  float* errb = (float*)(uni + 2536448);                // 2.05 MB  (scan -> mfilter)
  float* pgo  = (float*)(uni + 4587520);                // 10.49 MB (mfilter -> k_go)
  // late residents:
  float* gfp  = (float*)(uni);                          // 11.47 MB (k_gf)
  float* grp  = (float*)(uni + 11468800);               // 8.39 MB  (k_gr)

  k_wsplit<<<(N_HID*88 + 255)/256, 256, 0, stream>>>(W1, WH, WL);
  k_prep_t2<<<(N_HID*N_HID + 255)/256, 256, 0, stream>>>(Wr, Wo, WRT, WoT);
  k_prep_sums<<<(N_HID + N_OUT + 255)/256, 256, 0, stream>>>(Wr, Wo, Srow, SOs, tmax);
  dim3 gg(NK/128, N_HID/128);
  k_gemm<<<gg, 256, 0, stream>>>(x, WH, WL, INL);
  k_scan<<<BB, 64, 0, stream>>>(INL, label, WoT, WRT, Srow, SOs, hsb, outs, errb);
  k_mfilter<<<(BB*N_HID)/256, 256, 0, stream>>>(INL, errb, hsb, Wo, tmax, pgo);
  k_go<<<(N_OUT*N_HID)/64, 256, 0, stream>>>(pgo, go);
  dim3 ggf(8, 11, NCH); k_gf<<<ggf, 256, 0, stream>>>(INL, x, tmax, gfp);
  dim3 ggr(8, 8, NCH);  k_gr<<<ggr, 256, 0, stream>>>(INL, hsb, tmax, grp);
  k_gfred<<<(N_HID*N_IN + 255)/256, 256, 0, stream>>>(gfp, gf);
  k_grred<<<(N_HID*N_HID + 255)/256, 256, 0, stream>>>(grp, gr);
}

// Round 11
// 378.013 us; speedup vs baseline: 1.9741x; 1.3655x over previous
//
#include <hip/hip_runtime.h>
#include <cstdint>
#include <cstddef>

#define N_IN  700
#define N_INP 704           // K padded to 32
#define N_HID 512
#define N_OUT 20
#define BB    256
#define TT    100
#define NK    (BB*TT)       // 25600
#define NCH   8             // split-k chunks for gf/gr

__device__ __constant__ const float TAU   = 0.6f;
__device__ __constant__ const float TAU_O = 0.6f;
__device__ __constant__ const float THR   = 0.6f;
__device__ __constant__ const float GAM   = 0.3f;

typedef float f32x4 __attribute__((ext_vector_type(4)));
typedef __bf16 bf16x8 __attribute__((ext_vector_type(8)));

__device__ __forceinline__ unsigned short f2bf_rne(float f) {
  uint32_t b = __builtin_bit_cast(uint32_t, f);
  uint32_t r = (b + 0x7FFFu + ((b >> 16) & 1u)) >> 16;
  return (unsigned short)r;
}
__device__ __forceinline__ float bf2f(unsigned short u) {
  uint32_t b = ((uint32_t)u) << 16;
  return __builtin_bit_cast(float, b);
}

// ---------------- prep: W split into hi+lo bf16, [r][i] layout padded to 704 ----------------
__global__ void k_wsplit(const float* __restrict__ W1,
                         unsigned short* __restrict__ WH,
                         unsigned short* __restrict__ WL) {
  int g = blockIdx.x*256 + threadIdx.x;
  if (g >= N_HID*88) return;
  int r = g / 88, c = g - (g/88)*88;
  int ib = c*8;
  unsigned short h[8], l[8];
  #pragma unroll
  for (int j = 0; j < 8; ++j) {
    int i = ib + j;
    float v = (i < N_IN) ? W1[r*N_IN + i] : 0.f;
    unsigned short hh = f2bf_rne(v);
    float res = v - bf2f(hh);
    h[j] = hh;
    l[j] = f2bf_rne(res);
  }
  uint4 hv = make_uint4((uint32_t)h[0] | ((uint32_t)h[1]<<16), (uint32_t)h[2] | ((uint32_t)h[3]<<16),
                        (uint32_t)h[4] | ((uint32_t)h[5]<<16), (uint32_t)h[6] | ((uint32_t)h[7]<<16));
  uint4 lv = make_uint4((uint32_t)l[0] | ((uint32_t)l[1]<<16), (uint32_t)l[2] | ((uint32_t)l[3]<<16),
                        (uint32_t)l[4] | ((uint32_t)l[5]<<16), (uint32_t)l[6] | ((uint32_t)l[7]<<16));
  *(uint4*)(WH + (size_t)r*N_INP + ib) = hv;
  *(uint4*)(WL + (size_t)r*N_INP + ib) = lv;
}

__global__ void k_prep_t2(const float* __restrict__ Wr, const float* __restrict__ Wo,
                          float* __restrict__ WRT, float* __restrict__ WoT) {
  int g = blockIdx.x*256 + threadIdx.x;
  if (g < N_HID*N_HID) {
    int j = g >> 9, r = g & 511;
    WRT[g] = Wr[r*N_HID + j];
  }
  if (g < N_HID*N_OUT) {
    int r = g / N_OUT, o = g - r*N_OUT;
    WoT[g] = Wo[o*N_HID + r];
  }
}
// NOTE: summation order of Srow/SOs is spike-determining — keep serial order exactly.
__global__ void k_prep_sums(const float* __restrict__ Wr, const float* __restrict__ Wo,
                            float* __restrict__ Srow, float* __restrict__ SOs,
                            int* __restrict__ tmax) {
  int g = blockIdx.x*256 + threadIdx.x;
  if (g < N_HID) {
    float s = 0.f;
    for (int j = 0; j < N_HID; ++j) s += Wr[g*N_HID + j];
    Srow[g] = s;
  } else if (g < N_HID + N_OUT) {
    int o = g - N_HID;
    float s = 0.f;
    for (int r = 0; r < N_HID; ++r) s += Wo[o*N_HID + r];
    SOs[o] = s;
  }
  if (g < BB) tmax[g] = 0;
}

// ---------------- phase A: INL = X @ (WH^T + WL^T), MFMA split-bf16 ----------------
__global__ __launch_bounds__(256) void k_gemm(const float* __restrict__ x,
                                              const unsigned short* __restrict__ WH,
                                              const unsigned short* __restrict__ WL,
                                              float* __restrict__ INL) {
  __shared__ __align__(16) unsigned short sA [128*32];
  __shared__ __align__(16) unsigned short sBh[128*32];
  __shared__ __align__(16) unsigned short sBl[128*32];
  const int tid = threadIdx.x, lane = tid & 63, w = tid >> 6;
  const int k0 = blockIdx.x * 128;
  const int c0 = blockIdx.y * 128;
  const int wr = w >> 1, wc = w & 1;
  const int fr = lane & 15, fk = lane >> 4;

  const int a_r  = tid >> 1;
  const int a_cb = (tid & 1) * 16;
  const int b_r  = tid >> 2;
  const int b_c  = (tid & 3) * 8;

  const float* xr = x + (size_t)(k0 + a_r) * N_IN;
  const unsigned short* gh = WH + (size_t)(c0 + b_r) * N_INP;
  const unsigned short* gl = WL + (size_t)(c0 + b_r) * N_INP;

  f32x4 acc[4][4];
  #pragma unroll
  for (int m = 0; m < 4; ++m)
    #pragma unroll
    for (int n = 0; n < 4; ++n)
      acc[m][n] = (f32x4){0.f, 0.f, 0.f, 0.f};

  for (int s = 0; s < N_INP/32; ++s) {
    const int i0 = s * 32;
    float av[16];
    const int col0 = i0 + a_cb;
    if (col0 + 16 <= N_IN) {
      float4 t0 = *(const float4*)(xr + col0);
      float4 t1 = *(const float4*)(xr + col0 + 4);
      float4 t2 = *(const float4*)(xr + col0 + 8);
      float4 t3 = *(const float4*)(xr + col0 + 12);
      av[0]=t0.x; av[1]=t0.y; av[2]=t0.z; av[3]=t0.w;
      av[4]=t1.x; av[5]=t1.y; av[6]=t1.z; av[7]=t1.w;
      av[8]=t2.x; av[9]=t2.y; av[10]=t2.z; av[11]=t2.w;
      av[12]=t3.x; av[13]=t3.y; av[14]=t3.z; av[15]=t3.w;
    } else {
      #pragma unroll
      for (int j = 0; j < 16; ++j) av[j] = (col0 + j < N_IN) ? xr[col0 + j] : 0.f;
    }
    uint32_t us[8];
    #pragma unroll
    for (int p = 0; p < 8; ++p) {
      uint32_t lo = __builtin_bit_cast(uint32_t, av[2*p])   >> 16;
      uint32_t hi = __builtin_bit_cast(uint32_t, av[2*p+1]) & 0xFFFF0000u;
      us[p] = hi | lo;
    }
    *(uint4*)&sA[a_r*32 + a_cb]     = make_uint4(us[0], us[1], us[2], us[3]);
    *(uint4*)&sA[a_r*32 + a_cb + 8] = make_uint4(us[4], us[5], us[6], us[7]);
    *(uint4*)&sBh[b_r*32 + b_c]      = *(const uint4*)(gh + i0 + b_c);
    *(uint4*)&sBh[(b_r+64)*32 + b_c] = *(const uint4*)(gh + (size_t)64*N_INP + i0 + b_c);
    *(uint4*)&sBl[b_r*32 + b_c]      = *(const uint4*)(gl + i0 + b_c);
    *(uint4*)&sBl[(b_r+64)*32 + b_c] = *(const uint4*)(gl + (size_t)64*N_INP + i0 + b_c);
    __syncthreads();

    bf16x8 a[4], bh[4], bl[4];
    #pragma unroll
    for (int m = 0; m < 4; ++m)
      a[m] = *(const bf16x8*)&sA[(wr*64 + m*16 + fr)*32 + fk*8];
    #pragma unroll
    for (int n = 0; n < 4; ++n) {
      bh[n] = *(const bf16x8*)&sBh[(wc*64 + n*16 + fr)*32 + fk*8];
      bl[n] = *(const bf16x8*)&sBl[(wc*64 + n*16 + fr)*32 + fk*8];
    }
    #pragma unroll
    for (int m = 0; m < 4; ++m)
      #pragma unroll
      for (int n = 0; n < 4; ++n) {
        acc[m][n] = __builtin_amdgcn_mfma_f32_16x16x32_bf16(a[m], bh[n], acc[m][n], 0, 0, 0);
        acc[m][n] = __builtin_amdgcn_mfma_f32_16x16x32_bf16(a[m], bl[n], acc[m][n], 0, 0, 0);
      }
    __syncthreads();
  }
  #pragma unroll
  for (int m = 0; m < 4; ++m) {
    #pragma unroll
    for (int n = 0; n < 4; ++n) {
      #pragma unroll
      for (int reg = 0; reg < 4; ++reg) {
        const int row = k0 + wr*64 + m*16 + (lane>>4)*4 + reg;
        const int col = c0 + wc*64 + n*16 + fr;
        INL[(size_t)row*N_HID + col] = acc[m][n][reg];
      }
    }
  }
}

// ---------------- phase B: one WAVE per batch row; no go-accum (reg budget!) ----------------
// lane owns neurons r = j*64+lane (j=0..7); output neuron o = lane (lane<20).
__global__ __launch_bounds__(64, 1) void k_scan(
    float* __restrict__ INL, const float* __restrict__ label,
    const float* __restrict__ WoT, const float* __restrict__ WRT,
    const float* __restrict__ Srow, const float* __restrict__ SOs,
    unsigned long long* __restrict__ hsbits, float* __restrict__ outs,
    float* __restrict__ errb)
{
  __shared__ int list[N_HID];                     // single wave: no barriers needed
  const int b = blockIdx.x, lane = threadIdx.x;
  const size_t base = (size_t)b*TT;
  float srw[8], hm[8], curv[8], nxtv[8];
  int hs[8];
  #pragma unroll
  for (int j = 0; j < 8; ++j) { srw[j] = Srow[j*64 + lane]; hm[j] = 0.f; hs[j] = 0; }
  #pragma unroll
  for (int j = 0; j < 8; ++j) curv[j] = INL[base*N_HID + j*64 + lane];
  #pragma unroll
  for (int j = 0; j < 8; ++j) nxtv[j] = INL[(base+1)*N_HID + j*64 + lane];
  const float SOsl = (lane < N_OUT) ? SOs[lane] : 0.f;
  float lab = (lane < N_OUT) ? label[base*N_OUT + lane] : 0.f;
  float om = 0.f; int osb = 0;
  int cnt_prev = 0, mode_prev = 0;

  for (int t = 0; t < TT; ++t) {
    const size_t k = base + t;
    // 2-deep prefetch of IN, 1-deep of label
    float nn[8];
    const size_t k2 = (t + 2 < TT) ? (k + 2) : (base + TT - 1);
    #pragma unroll
    for (int j = 0; j < 8; ++j) nn[j] = INL[k2*N_HID + j*64 + lane];
    const size_t k1 = (t + 1 < TT) ? (k + 1) : k;
    const float labn = (lane < N_OUT) ? label[k1*N_OUT + lane] : 0.f;

    // recurrent drive from prev-step list (wave-uniform control)
    float rec[8];
    if (cnt_prev == 0 && mode_prev == 1) {        // all spiked
      #pragma unroll
      for (int j = 0; j < 8; ++j) rec[j] = srw[j];
    } else if (cnt_prev == 0) {
      #pragma unroll
      for (int j = 0; j < 8; ++j) rec[j] = 0.f;
    } else {
      float racc[8];
      #pragma unroll
      for (int j = 0; j < 8; ++j) racc[j] = 0.f;
      for (int it = 0; it < cnt_prev; ++it) {
        const int jj = list[it];
        #pragma unroll
        for (int j = 0; j < 8; ++j) racc[j] += WRT[jj*N_HID + j*64 + lane];
      }
      #pragma unroll
      for (int j = 0; j < 8; ++j) rec[j] = mode_prev ? (srw[j] - racc[j]) : racc[j];
    }

    // hidden membrane + spikes
    float nhm[8]; int nhs[8]; unsigned long long m[8];
    #pragma unroll
    for (int j = 0; j < 8; ++j)
      nhm[j] = TAU*hm[j]*(hs[j] ? 0.f : 1.f) + curv[j] + rec[j];
    #pragma unroll
    for (int j = 0; j < 8; ++j) { nhs[j] = (nhm[j] >= THR) ? 1 : 0; m[j] = __ballot(nhs[j] != 0); }
    int pcs[8], ctot = 0;
    #pragma unroll
    for (int j = 0; j < 8; ++j) { pcs[j] = (int)__popcll(m[j]); ctot += pcs[j]; }
    if (lane == 0) {
      #pragma unroll
      for (int j = 0; j < 8; ++j) hsbits[k*8 + j] = m[j];
    }
    const int mode = (ctot <= 256) ? 0 : 1;
    const int cnt  = mode ? (512 - ctot) : ctot;  // cnt==0 && mode==1 -> all spiked

    // build list (slow steps only) — same compaction order as earlier rounds
    float drv;
    if (cnt != 0) {
      int pre[8];
      pre[0] = 0;
      #pragma unroll
      for (int q = 1; q < 8; ++q) pre[q] = pre[q-1] + (mode ? 64 - pcs[q-1] : pcs[q-1]);
      const unsigned long long below = (1ULL << lane) - 1ULL;
      #pragma unroll
      for (int q = 0; q < 8; ++q) {
        const unsigned long long sm = mode ? ~m[q] : m[q];
        if ((sm >> lane) & 1ULL)
          list[pre[q] + (int)__popcll(sm & below)] = q*64 + lane;
      }
      // output drive via WoT (lane < 20)
      float cdr = 0.f;
      for (int it = 0; it < cnt; ++it) {
        const int jj = list[it];
        cdr += (lane < N_OUT) ? WoT[jj*N_OUT + lane] : 0.f;
      }
      drv = mode ? (SOsl - cdr) : cdr;
    } else {
      drv = mode ? SOsl : 0.f;
    }

    // output neuron update (o = lane)
    om = TAU*om*(osb ? 0.f : 1.f) + drv;
    const int nos = (om >= THR) ? 1 : 0;
    if (lane < N_OUT) {
      const float osf = nos ? 1.f : 0.f;
      outs[k*N_OUT + lane] = osf;
      errb[k*N_OUT + lane] = osf - lab;
    }
    osb = nos;

    // h' store (in place over IN)
    #pragma unroll
    for (int j = 0; j < 8; ++j) {
      const float a  = fabsf(nhm[j] - THR) / THR;
      const float ht = GAM * fmaxf(0.f, 1.f - a);
      INL[k*N_HID + j*64 + lane] = ht;
      hm[j] = nhm[j]; hs[j] = nhs[j];
    }
    #pragma unroll
    for (int j = 0; j < 8; ++j) { curv[j] = nxtv[j]; nxtv[j] = nn[j]; }
    cnt_prev = cnt; mode_prev = mode;
    lab = labn;
  }
}

// ---------------- phase C: fused L->M reverse filter + go accumulation ----------------
// Block = (b, half of r). errb staged in LDS; F precomputed in LDS (threads 0..19,
// same backward recurrence/FP order as r10). (256,1) releases the VGPR cap: woc/goacc
// stay register-resident (r10's VGPR=52 spill was the 194us).
__global__ __launch_bounds__(256, 1) void k_mfilter(float* __restrict__ INL,
                                                    const float* __restrict__ errb,
                                                    const unsigned long long* __restrict__ hsbits,
                                                    const float* __restrict__ Wo,
                                                    int* __restrict__ tmax,
                                                    float* __restrict__ pgo) {
  __shared__ __align__(16) float sE[TT][N_OUT];   // 8000 B
  __shared__ __align__(16) float sF[TT][N_OUT];   // 8000 B
  const int b = blockIdx.x >> 1;
  const int r = (blockIdx.x & 1)*256 + threadIdx.x;
  const int hw = r >> 6, sh = r & 63;
  const size_t rb = (size_t)b*TT;

  for (int idx = threadIdx.x; idx < TT*N_OUT; idx += 256)
    (&sE[0][0])[idx] = errb[rb*N_OUT + idx];
  __syncthreads();
  if (threadIdx.x < N_OUT) {
    const int o = threadIdx.x;
    float f = 0.f;
    for (int t = TT - 1; t >= 0; --t) {
      f = sE[t][o] + TAU_O*f;                      // same order as r10's F update
      sF[t][o] = f;
    }
  }
  float woc[N_OUT], goacc[N_OUT];
  #pragma unroll
  for (int o = 0; o < N_OUT; ++o) { woc[o] = Wo[o*N_HID + r]; goacc[o] = 0.f; }
  __syncthreads();

  float mval = 0.f; int last = -1;
  float hcur = INL[(rb + TT - 1)*N_HID + r];
  unsigned long long word = hsbits[(rb + TT - 1)*8 + hw];
  for (int t = TT - 1; t >= 0; --t) {
    const float hnxt = (t > 0) ? INL[(rb + t - 1)*N_HID + r] : 0.f;
    const unsigned long long word_n = (t > 0) ? hsbits[(rb + t - 1)*8 + hw] : 0ULL;
    float ev[N_OUT], fv[N_OUT];
    #pragma unroll
    for (int q = 0; q < 5; ++q) {
      const float4 e4 = *(const float4*)&sE[t][4*q];
      const float4 f4 = *(const float4*)&sF[t][4*q];
      ev[4*q+0]=e4.x; ev[4*q+1]=e4.y; ev[4*q+2]=e4.z; ev[4*q+3]=e4.w;
      fv[4*q+0]=f4.x; fv[4*q+1]=f4.y; fv[4*q+2]=f4.z; fv[4*q+3]=f4.w;
    }
    float d = 0.f;
    #pragma unroll
    for (int o = 0; o < N_OUT; ++o) d += ev[o] * woc[o];
    if ((word >> sh) & 1ULL) {
      #pragma unroll
      for (int o = 0; o < N_OUT; ++o) goacc[o] += fv[o];
    }
    const float v = d*hcur + TAU*mval;
    INL[(rb + t)*N_HID + r] = v;
    mval = v;
    if (v != 0.f && last < 0) last = t;
    hcur = hnxt; word = word_n;
  }
  if (last >= 0) atomicMax(tmax + b, last + 1);
  #pragma unroll
  for (int o = 0; o < N_OUT; ++o)
    pgo[((size_t)b*N_OUT + o)*N_HID + r] = goacc[o];
}

// ---------------- phase D: go = 0.1 * sum_b pgo[b]  (160 blocks, 4-way b-split, ordered reduce) ----------------
__global__ __launch_bounds__(256) void k_go(const float* __restrict__ pgo, float* __restrict__ go) {
  __shared__ float red[4][64];
  const int l = threadIdx.x & 63;
  const int ch = threadIdx.x >> 6;
  const int col = blockIdx.x*64 + l;
  float s = 0.f;
  for (int b2 = ch*64; b2 < ch*64 + 64; ++b2)
    s += pgo[(size_t)b2*(N_OUT*N_HID) + col];
  red[ch][l] = s;
  __syncthreads();
  if (ch == 0) go[col] = 0.1f*(((red[0][l] + red[1][l]) + red[2][l]) + red[3][l]);
}

// ---------------- phase D: gf partials over b-chunks ----------------
__global__ __launch_bounds__(256) void k_gf(const float* __restrict__ M, const float* __restrict__ x,
                                            const int* __restrict__ tmax,
                                            float* __restrict__ gfp) {
  const int lane = threadIdx.x & 63, w = threadIdx.x >> 6;
  const int r  = blockIdx.x*64 + lane;
  const int i0 = blockIdx.y*64 + w*16;
  const int ch = blockIdx.z;
  const int b_lo = ch * (BB/NCH);
  __shared__ int cnt_sh[BB/NCH];
  if (threadIdx.x < BB/NCH) cnt_sh[threadIdx.x] = tmax[b_lo + threadIdx.x];
  __syncthreads();
  float acc[16];
  #pragma unroll
  for (int ii = 0; ii < 16; ++ii) acc[ii] = 0.f;
  int xi = i0 + (lane & 15); if (xi > N_IN - 1) xi = N_IN - 1;
  for (int bi = 0; bi < BB/NCH; ++bi) {
    const int ct = cnt_sh[bi];
    if (ct == 0) continue;
    const size_t kb = (size_t)(b_lo + bi)*TT;
    float mv = M[kb*N_HID + r];
    float xv = x[kb*N_IN + xi];
    for (int t = 0; t < ct; ++t) {
      float mv_n = 0.f, xv_n = 0.f;
      if (t + 1 < ct) {
        mv_n = M[(kb + t + 1)*N_HID + r];
        xv_n = x[(kb + t + 1)*N_IN + xi];
      }
      #pragma unroll
      for (int ii = 0; ii < 16; ++ii) acc[ii] += mv * __shfl(xv, ii);
      mv = mv_n; xv = xv_n;
    }
  }
  #pragma unroll
  for (int ii = 0; ii < 16; ++ii) {
    const int i = i0 + ii;
    if (i < N_IN) gfp[(size_t)ch*(N_HID*N_IN) + (size_t)r*N_IN + i] = acc[ii];
  }
}

// ---------------- phase D: gr partials over b-chunks ----------------
__global__ __launch_bounds__(256) void k_gr(const float* __restrict__ M,
                                            const unsigned long long* __restrict__ hsbits,
                                            const int* __restrict__ tmax,
                                            float* __restrict__ grp) {
  const int lane = threadIdx.x & 63, w = threadIdx.x >> 6;
  const int r  = blockIdx.x*64 + lane;
  const int h0 = blockIdx.y*64 + w*16;
  const int ch = blockIdx.z;
  const int b_lo = ch * (BB/NCH);
  __shared__ int cnt_sh[BB/NCH];
  if (threadIdx.x < BB/NCH) cnt_sh[threadIdx.x] = tmax[b_lo + threadIdx.x];
  __syncthreads();
  float acc[16];
  #pragma unroll
  for (int ii = 0; ii < 16; ++ii) acc[ii] = 0.f;
  const int hw = h0 >> 6, sh = h0 & 63;
  for (int bi = 0; bi < BB/NCH; ++bi) {
    const int ct = cnt_sh[bi];
    if (ct == 0) continue;
    const size_t kb = (size_t)(b_lo + bi)*TT;
    float mv = M[kb*N_HID + r];
    unsigned long long word = hsbits[kb*8 + hw];
    for (int t = 0; t < ct; ++t) {
      float mv_n = 0.f; unsigned long long word_n = 0ULL;
      if (t + 1 < ct) {
        mv_n = M[(kb + t + 1)*N_HID + r];
        word_n = hsbits[(kb + t + 1)*8 + hw];
      }
      #pragma unroll
      for (int ii = 0; ii < 16; ++ii)
        if ((word >> (sh + ii)) & 1ULL) acc[ii] += mv;
      mv = mv_n; word = word_n;
    }
  }
  #pragma unroll
  for (int ii = 0; ii < 16; ++ii)
    grp[(size_t)ch*(N_HID*N_HID) + (size_t)r*N_HID + h0 + ii] = acc[ii];
}

// ---------------- phase D: deterministic partial reductions ----------------
__global__ void k_gfred(const float* __restrict__ gfp, float* __restrict__ gf) {
  const int g = blockIdx.x*256 + threadIdx.x;
  if (g < N_HID*N_IN) {
    float s = 0.f;
    #pragma unroll
    for (int c = 0; c < NCH; ++c) s += gfp[(size_t)c*(N_HID*N_IN) + g];
    gf[g] = 0.1f*s;
  }
}
__global__ void k_grred(const float* __restrict__ grp, float* __restrict__ gr) {
  const int g = blockIdx.x*256 + threadIdx.x;
  if (g < N_HID*N_HID) {
    float s = 0.f;
    #pragma unroll
    for (int c = 0; c < NCH; ++c) s += grp[(size_t)c*(N_HID*N_HID) + g];
    gr[g] = 0.1f*s;
  }
}

extern "C" void kernel_launch(void* const* d_in, const int* in_sizes, int n_in,
                              void* d_out, int out_size, void* d_ws, size_t ws_size,
                              hipStream_t stream) {
  const float* x     = (const float*)d_in[0];
  const float* label = (const float*)d_in[1];
  const float* W1    = (const float*)d_in[2];
  const float* Wr    = (const float*)d_in[3];
  const float* Wo    = (const float*)d_in[4];

  float* out  = (float*)d_out;
  float* outs = out;                                    // [256][100][20]
  float* gf   = out + 512000;                           // [512][700]
  float* gr   = out + 512000 + 358400;                  // [512][512]
  float* go   = out + 512000 + 358400 + 262144;         // [20][512]

  char* ws = (char*)d_ws;
  size_t off = 0;
  auto alloc = [&](size_t bytes) -> char* {
    char* p = ws + off;
    off += (bytes + 255) & ~(size_t)255;
    return p;
  };
  float* INL = (float*)alloc((size_t)NK*N_HID*sizeof(float));                    // 52.43 MB
  unsigned long long* hsb = (unsigned long long*)alloc((size_t)NK*8*sizeof(unsigned long long)); // 1.64 MB
  int* tmax = (int*)alloc((size_t)BB*sizeof(int));
  char* uni = alloc((size_t)20971520);                                           // 20 MB union region

  // early residents of uni (all dead before k_gf):
  unsigned short* WH = (unsigned short*)(uni);          // 0.72 MB  (dead after gemm)
  unsigned short* WL = (unsigned short*)(uni + 720896); // 0.72 MB  (dead after gemm)
  float* WRT  = (float*)(uni + 1441792);                // 1.05 MB  (dead after scan)
  float* Srow = (float*)(uni + 2490368);
  float* SOs  = (float*)(uni + 2492416);
  float* WoT  = (float*)(uni + 2494464);                // 40 KB    (dead after scan)
  float* errb = (float*)(uni + 2536448);                // 2.05 MB  (scan -> mfilter)
  float* pgo  = (float*)(uni + 4587520);                // 10.49 MB (mfilter -> k_go)
  // late residents:
  float* gfp  = (float*)(uni);                          // 11.47 MB (k_gf)
  float* grp  = (float*)(uni + 11468800);               // 8.39 MB  (k_gr)

  k_wsplit<<<(N_HID*88 + 255)/256, 256, 0, stream>>>(W1, WH, WL);
  k_prep_t2<<<(N_HID*N_HID + 255)/256, 256, 0, stream>>>(Wr, Wo, WRT, WoT);
  k_prep_sums<<<(N_HID + N_OUT + 255)/256, 256, 0, stream>>>(Wr, Wo, Srow, SOs, tmax);
  dim3 gg(NK/128, N_HID/128);
  k_gemm<<<gg, 256, 0, stream>>>(x, WH, WL, INL);
  k_scan<<<BB, 64, 0, stream>>>(INL, label, WoT, WRT, Srow, SOs, hsb, outs, errb);
  k_mfilter<<<(BB*N_HID)/256, 256, 0, stream>>>(INL, errb, hsb, Wo, tmax, pgo);
  k_go<<<(N_OUT*N_HID)/64, 256, 0, stream>>>(pgo, go);
  dim3 ggf(8, 11, NCH); k_gf<<<ggf, 256, 0, stream>>>(INL, x, tmax, gfp);
  dim3 ggr(8, 8, NCH);  k_gr<<<ggr, 256, 0, stream>>>(INL, hsb, tmax, grp);
  k_gfred<<<(N_HID*N_IN + 255)/256, 256, 0, stream>>>(gfp, gf);
  k_grred<<<(N_HID*N_HID + 255)/256, 256, 0, stream>>>(grp, gr);
}

// Round 12
// 358.038 us; speedup vs baseline: 2.0842x; 1.0558x over previous
//
#include <hip/hip_runtime.h>
#include <cstdint>
#include <cstddef>

#define N_IN  700
#define N_INP 704           // K padded to 32
#define N_HID 512
#define N_OUT 20
#define BB    256
#define TT    100
#define NK    (BB*TT)       // 25600
#define NCH   8             // split-k chunks for gf/gr

__device__ __constant__ const float TAU   = 0.6f;
__device__ __constant__ const float TAU_O = 0.6f;
__device__ __constant__ const float THR   = 0.6f;
__device__ __constant__ const float GAM   = 0.3f;

typedef float f32x4 __attribute__((ext_vector_type(4)));
typedef __bf16 bf16x8 __attribute__((ext_vector_type(8)));

__device__ __forceinline__ unsigned short f2bf_rne(float f) {
  uint32_t b = __builtin_bit_cast(uint32_t, f);
  uint32_t r = (b + 0x7FFFu + ((b >> 16) & 1u)) >> 16;
  return (unsigned short)r;
}
__device__ __forceinline__ float bf2f(unsigned short u) {
  uint32_t b = ((uint32_t)u) << 16;
  return __builtin_bit_cast(float, b);
}

// ---------------- prep: W split into hi+lo bf16, [r][i] layout padded to 704 ----------------
__global__ void k_wsplit(const float* __restrict__ W1,
                         unsigned short* __restrict__ WH,
                         unsigned short* __restrict__ WL) {
  int g = blockIdx.x*256 + threadIdx.x;
  if (g >= N_HID*88) return;
  int r = g / 88, c = g - (g/88)*88;
  int ib = c*8;
  unsigned short h[8], l[8];
  #pragma unroll
  for (int j = 0; j < 8; ++j) {
    int i = ib + j;
    float v = (i < N_IN) ? W1[r*N_IN + i] : 0.f;
    unsigned short hh = f2bf_rne(v);
    float res = v - bf2f(hh);
    h[j] = hh;
    l[j] = f2bf_rne(res);
  }
  uint4 hv = make_uint4((uint32_t)h[0] | ((uint32_t)h[1]<<16), (uint32_t)h[2] | ((uint32_t)h[3]<<16),
                        (uint32_t)h[4] | ((uint32_t)h[5]<<16), (uint32_t)h[6] | ((uint32_t)h[7]<<16));
  uint4 lv = make_uint4((uint32_t)l[0] | ((uint32_t)l[1]<<16), (uint32_t)l[2] | ((uint32_t)l[3]<<16),
                        (uint32_t)l[4] | ((uint32_t)l[5]<<16), (uint32_t)l[6] | ((uint32_t)l[7]<<16));
  *(uint4*)(WH + (size_t)r*N_INP + ib) = hv;
  *(uint4*)(WL + (size_t)r*N_INP + ib) = lv;
}

__global__ void k_prep_t2(const float* __restrict__ Wr, const float* __restrict__ Wo,
                          float* __restrict__ WRT, float* __restrict__ WoT) {
  int g = blockIdx.x*256 + threadIdx.x;
  if (g < N_HID*N_HID) {
    int j = g >> 9, r = g & 511;
    WRT[g] = Wr[r*N_HID + j];
  }
  if (g < N_HID*N_OUT) {
    int r = g / N_OUT, o = g - r*N_OUT;
    WoT[g] = Wo[o*N_HID + r];
  }
}
// NOTE: summation order of Srow/SOs is spike-determining — keep serial order exactly.
__global__ void k_prep_sums(const float* __restrict__ Wr, const float* __restrict__ Wo,
                            float* __restrict__ Srow, float* __restrict__ SOs,
                            int* __restrict__ tmax) {
  int g = blockIdx.x*256 + threadIdx.x;
  if (g < N_HID) {
    float s = 0.f;
    for (int j = 0; j < N_HID; ++j) s += Wr[g*N_HID + j];
    Srow[g] = s;
  } else if (g < N_HID + N_OUT) {
    int o = g - N_HID;
    float s = 0.f;
    for (int r = 0; r < N_HID; ++r) s += Wo[o*N_HID + r];
    SOs[o] = s;
  }
  if (g < BB) tmax[g] = 0;
}

// ---------------- phase A: INL = X @ (WH^T + WL^T), MFMA split-bf16 ----------------
__global__ __launch_bounds__(256) void k_gemm(const float* __restrict__ x,
                                              const unsigned short* __restrict__ WH,
                                              const unsigned short* __restrict__ WL,
                                              float* __restrict__ INL) {
  __shared__ __align__(16) unsigned short sA [128*32];
  __shared__ __align__(16) unsigned short sBh[128*32];
  __shared__ __align__(16) unsigned short sBl[128*32];
  const int tid = threadIdx.x, lane = tid & 63, w = tid >> 6;
  const int k0 = blockIdx.x * 128;
  const int c0 = blockIdx.y * 128;
  const int wr = w >> 1, wc = w & 1;
  const int fr = lane & 15, fk = lane >> 4;

  const int a_r  = tid >> 1;
  const int a_cb = (tid & 1) * 16;
  const int b_r  = tid >> 2;
  const int b_c  = (tid & 3) * 8;

  const float* xr = x + (size_t)(k0 + a_r) * N_IN;
  const unsigned short* gh = WH + (size_t)(c0 + b_r) * N_INP;
  const unsigned short* gl = WL + (size_t)(c0 + b_r) * N_INP;

  f32x4 acc[4][4];
  #pragma unroll
  for (int m = 0; m < 4; ++m)
    #pragma unroll
    for (int n = 0; n < 4; ++n)
      acc[m][n] = (f32x4){0.f, 0.f, 0.f, 0.f};

  for (int s = 0; s < N_INP/32; ++s) {
    const int i0 = s * 32;
    float av[16];
    const int col0 = i0 + a_cb;
    if (col0 + 16 <= N_IN) {
      float4 t0 = *(const float4*)(xr + col0);
      float4 t1 = *(const float4*)(xr + col0 + 4);
      float4 t2 = *(const float4*)(xr + col0 + 8);
      float4 t3 = *(const float4*)(xr + col0 + 12);
      av[0]=t0.x; av[1]=t0.y; av[2]=t0.z; av[3]=t0.w;
      av[4]=t1.x; av[5]=t1.y; av[6]=t1.z; av[7]=t1.w;
      av[8]=t2.x; av[9]=t2.y; av[10]=t2.z; av[11]=t2.w;
      av[12]=t3.x; av[13]=t3.y; av[14]=t3.z; av[15]=t3.w;
    } else {
      #pragma unroll
      for (int j = 0; j < 16; ++j) av[j] = (col0 + j < N_IN) ? xr[col0 + j] : 0.f;
    }
    uint32_t us[8];
    #pragma unroll
    for (int p = 0; p < 8; ++p) {
      uint32_t lo = __builtin_bit_cast(uint32_t, av[2*p])   >> 16;
      uint32_t hi = __builtin_bit_cast(uint32_t, av[2*p+1]) & 0xFFFF0000u;
      us[p] = hi | lo;
    }
    *(uint4*)&sA[a_r*32 + a_cb]     = make_uint4(us[0], us[1], us[2], us[3]);
    *(uint4*)&sA[a_r*32 + a_cb + 8] = make_uint4(us[4], us[5], us[6], us[7]);
    *(uint4*)&sBh[b_r*32 + b_c]      = *(const uint4*)(gh + i0 + b_c);
    *(uint4*)&sBh[(b_r+64)*32 + b_c] = *(const uint4*)(gh + (size_t)64*N_INP + i0 + b_c);
    *(uint4*)&sBl[b_r*32 + b_c]      = *(const uint4*)(gl + i0 + b_c);
    *(uint4*)&sBl[(b_r+64)*32 + b_c] = *(const uint4*)(gl + (size_t)64*N_INP + i0 + b_c);
    __syncthreads();

    bf16x8 a[4], bh[4], bl[4];
    #pragma unroll
    for (int m = 0; m < 4; ++m)
      a[m] = *(const bf16x8*)&sA[(wr*64 + m*16 + fr)*32 + fk*8];
    #pragma unroll
    for (int n = 0; n < 4; ++n) {
      bh[n] = *(const bf16x8*)&sBh[(wc*64 + n*16 + fr)*32 + fk*8];
      bl[n] = *(const bf16x8*)&sBl[(wc*64 + n*16 + fr)*32 + fk*8];
    }
    #pragma unroll
    for (int m = 0; m < 4; ++m)
      #pragma unroll
      for (int n = 0; n < 4; ++n) {
        acc[m][n] = __builtin_amdgcn_mfma_f32_16x16x32_bf16(a[m], bh[n], acc[m][n], 0, 0, 0);
        acc[m][n] = __builtin_amdgcn_mfma_f32_16x16x32_bf16(a[m], bl[n], acc[m][n], 0, 0, 0);
      }
    __syncthreads();
  }
  #pragma unroll
  for (int m = 0; m < 4; ++m) {
    #pragma unroll
    for (int n = 0; n < 4; ++n) {
      #pragma unroll
      for (int reg = 0; reg < 4; ++reg) {
        const int row = k0 + wr*64 + m*16 + (lane>>4)*4 + reg;
        const int col = c0 + wc*64 + n*16 + fr;
        INL[(size_t)row*N_HID + col] = acc[m][n][reg];
      }
    }
  }
}

// ---------------- phase B: one WAVE per batch row; rotation-free unroll-4 prefetch ----------------
// lane owns neurons r = j*64+lane (j=0..7); output neuron o = lane (lane<20).
// Each of 4 persistent buffers ci is read at step t (t%4==i), then reloaded in-place with
// row t+4 AFTER the read — no rotation movs, so the s_waitcnt for each load sits ~3 full
// step-bodies downstream (r11's rotation forced a same-iteration wait = fake prefetch).
__global__ __launch_bounds__(64, 1) void k_scan(
    float* __restrict__ INL, const float* __restrict__ label,
    const float* __restrict__ WoT, const float* __restrict__ WRT,
    const float* __restrict__ Srow, const float* __restrict__ SOs,
    unsigned long long* __restrict__ hsbits, float* __restrict__ outs,
    float* __restrict__ errb)
{
  __shared__ int list[N_HID];                     // single wave: no barriers needed
  const int b = blockIdx.x, lane = threadIdx.x;
  const size_t base = (size_t)b*TT;
  float srw[8], hm[8];
  int hs[8];
  #pragma unroll
  for (int j = 0; j < 8; ++j) { srw[j] = Srow[j*64 + lane]; hm[j] = 0.f; hs[j] = 0; }
  const float SOsl = (lane < N_OUT) ? SOs[lane] : 0.f;
  float om = 0.f; int osb = 0;
  int cnt_prev = 0, mode_prev = 0;

  float c0[8], c1[8], c2[8], c3[8];
  #pragma unroll
  for (int j = 0; j < 8; ++j) {
    c0[j] = INL[(base+0)*N_HID + j*64 + lane];
    c1[j] = INL[(base+1)*N_HID + j*64 + lane];
    c2[j] = INL[(base+2)*N_HID + j*64 + lane];
    c3[j] = INL[(base+3)*N_HID + j*64 + lane];
  }
  float lb0 = (lane < N_OUT) ? label[(base+0)*N_OUT + lane] : 0.f;
  float lb1 = (lane < N_OUT) ? label[(base+1)*N_OUT + lane] : 0.f;
  float lb2 = (lane < N_OUT) ? label[(base+2)*N_OUT + lane] : 0.f;
  float lb3 = (lane < N_OUT) ? label[(base+3)*N_OUT + lane] : 0.f;

  auto STEP = [&](int t, float (&cv)[8], float &lb) {
    const size_t k = base + t;

    // recurrent drive from prev-step list (wave-uniform control)
    float rec[8];
    if (cnt_prev == 0 && mode_prev == 1) {        // all spiked
      #pragma unroll
      for (int j = 0; j < 8; ++j) rec[j] = srw[j];
    } else if (cnt_prev == 0) {
      #pragma unroll
      for (int j = 0; j < 8; ++j) rec[j] = 0.f;
    } else {
      float racc[8];
      #pragma unroll
      for (int j = 0; j < 8; ++j) racc[j] = 0.f;
      for (int it = 0; it < cnt_prev; ++it) {
        const int jj = list[it];
        #pragma unroll
        for (int j = 0; j < 8; ++j) racc[j] += WRT[jj*N_HID + j*64 + lane];
      }
      #pragma unroll
      for (int j = 0; j < 8; ++j) rec[j] = mode_prev ? (srw[j] - racc[j]) : racc[j];
    }

    // hidden membrane + spikes (reads cv — last use before in-place prefetch)
    float nhm[8]; int nhs[8]; unsigned long long m[8];
    #pragma unroll
    for (int j = 0; j < 8; ++j)
      nhm[j] = TAU*hm[j]*(hs[j] ? 0.f : 1.f) + cv[j] + rec[j];

    // in-place prefetch of row t+4 (issued after cv reads; consumed 4 steps later)
    const size_t kp = (t + 4 < TT) ? (k + 4) : (base + TT - 1);
    #pragma unroll
    for (int j = 0; j < 8; ++j) cv[j] = INL[kp*N_HID + j*64 + lane];
    const float lab_cur = lb;
    lb = (lane < N_OUT) ? label[kp*N_OUT + lane] : 0.f;

    #pragma unroll
    for (int j = 0; j < 8; ++j) { nhs[j] = (nhm[j] >= THR) ? 1 : 0; m[j] = __ballot(nhs[j] != 0); }
    int pcs[8], ctot = 0;
    #pragma unroll
    for (int j = 0; j < 8; ++j) { pcs[j] = (int)__popcll(m[j]); ctot += pcs[j]; }
    if (lane == 0) {
      #pragma unroll
      for (int j = 0; j < 8; ++j) hsbits[k*8 + j] = m[j];
    }
    const int mode = (ctot <= 256) ? 0 : 1;
    const int cnt  = mode ? (512 - ctot) : ctot;  // cnt==0 && mode==1 -> all spiked

    // build list (slow steps only) — same compaction order as earlier rounds
    float drv;
    if (cnt != 0) {
      int pre[8];
      pre[0] = 0;
      #pragma unroll
      for (int q = 1; q < 8; ++q) pre[q] = pre[q-1] + (mode ? 64 - pcs[q-1] : pcs[q-1]);
      const unsigned long long below = (1ULL << lane) - 1ULL;
      #pragma unroll
      for (int q = 0; q < 8; ++q) {
        const unsigned long long sm = mode ? ~m[q] : m[q];
        if ((sm >> lane) & 1ULL)
          list[pre[q] + (int)__popcll(sm & below)] = q*64 + lane;
      }
      float cdr = 0.f;
      for (int it = 0; it < cnt; ++it) {
        const int jj = list[it];
        cdr += (lane < N_OUT) ? WoT[jj*N_OUT + lane] : 0.f;
      }
      drv = mode ? (SOsl - cdr) : cdr;
    } else {
      drv = mode ? SOsl : 0.f;
    }

    // output neuron update (o = lane)
    om = TAU*om*(osb ? 0.f : 1.f) + drv;
    const int nos = (om >= THR) ? 1 : 0;
    if (lane < N_OUT) {
      const float osf = nos ? 1.f : 0.f;
      outs[k*N_OUT + lane] = osf;
      errb[k*N_OUT + lane] = osf - lab_cur;
    }
    osb = nos;

    // h' store (in place over IN)
    #pragma unroll
    for (int j = 0; j < 8; ++j) {
      const float a  = fabsf(nhm[j] - THR) / THR;
      const float ht = GAM * fmaxf(0.f, 1.f - a);
      INL[k*N_HID + j*64 + lane] = ht;
      hm[j] = nhm[j]; hs[j] = nhs[j];
    }
    cnt_prev = cnt; mode_prev = mode;
  };

  for (int tt = 0; tt < TT; tt += 4) {
    STEP(tt + 0, c0, lb0);
    STEP(tt + 1, c1, lb1);
    STEP(tt + 2, c2, lb2);
    STEP(tt + 3, c3, lb3);
  }
}

// ---------------- phase C: fused L->M reverse filter + go accumulation ----------------
__global__ __launch_bounds__(256, 1) void k_mfilter(float* __restrict__ INL,
                                                    const float* __restrict__ errb,
                                                    const unsigned long long* __restrict__ hsbits,
                                                    const float* __restrict__ Wo,
                                                    int* __restrict__ tmax,
                                                    float* __restrict__ pgo) {
  __shared__ __align__(16) float sE[TT][N_OUT];   // 8000 B
  __shared__ __align__(16) float sF[TT][N_OUT];   // 8000 B
  const int b = blockIdx.x >> 1;
  const int r = (blockIdx.x & 1)*256 + threadIdx.x;
  const int hw = r >> 6, sh = r & 63;
  const size_t rb = (size_t)b*TT;

  for (int idx = threadIdx.x; idx < TT*N_OUT; idx += 256)
    (&sE[0][0])[idx] = errb[rb*N_OUT + idx];
  __syncthreads();
  if (threadIdx.x < N_OUT) {
    const int o = threadIdx.x;
    float f = 0.f;
    for (int t = TT - 1; t >= 0; --t) {
      f = sE[t][o] + TAU_O*f;
      sF[t][o] = f;
    }
  }
  float woc[N_OUT], goacc[N_OUT];
  #pragma unroll
  for (int o = 0; o < N_OUT; ++o) { woc[o] = Wo[o*N_HID + r]; goacc[o] = 0.f; }
  __syncthreads();

  float mval = 0.f; int last = -1;
  float hcur = INL[(rb + TT - 1)*N_HID + r];
  unsigned long long word = hsbits[(rb + TT - 1)*8 + hw];
  for (int t = TT - 1; t >= 0; --t) {
    const float hnxt = (t > 0) ? INL[(rb + t - 1)*N_HID + r] : 0.f;
    const unsigned long long word_n = (t > 0) ? hsbits[(rb + t - 1)*8 + hw] : 0ULL;
    float ev[N_OUT], fv[N_OUT];
    #pragma unroll
    for (int q = 0; q < 5; ++q) {
      const float4 e4 = *(const float4*)&sE[t][4*q];
      const float4 f4 = *(const float4*)&sF[t][4*q];
      ev[4*q+0]=e4.x; ev[4*q+1]=e4.y; ev[4*q+2]=e4.z; ev[4*q+3]=e4.w;
      fv[4*q+0]=f4.x; fv[4*q+1]=f4.y; fv[4*q+2]=f4.z; fv[4*q+3]=f4.w;
    }
    float d = 0.f;
    #pragma unroll
    for (int o = 0; o < N_OUT; ++o) d += ev[o] * woc[o];
    if ((word >> sh) & 1ULL) {
      #pragma unroll
      for (int o = 0; o < N_OUT; ++o) goacc[o] += fv[o];
    }
    const float v = d*hcur + TAU*mval;
    INL[(rb + t)*N_HID + r] = v;
    mval = v;
    if (v != 0.f && last < 0) last = t;
    hcur = hnxt; word = word_n;
  }
  if (last >= 0) atomicMax(tmax + b, last + 1);
  #pragma unroll
  for (int o = 0; o < N_OUT; ++o)
    pgo[((size_t)b*N_OUT + o)*N_HID + r] = goacc[o];
}

// ---------------- phase D: go = 0.1 * sum_b pgo[b]  (160 blocks, 4-way b-split, ordered reduce) ----------------
__global__ __launch_bounds__(256) void k_go(const float* __restrict__ pgo, float* __restrict__ go) {
  __shared__ float red[4][64];
  const int l = threadIdx.x & 63;
  const int ch = threadIdx.x >> 6;
  const int col = blockIdx.x*64 + l;
  float s = 0.f;
  for (int b2 = ch*64; b2 < ch*64 + 64; ++b2)
    s += pgo[(size_t)b2*(N_OUT*N_HID) + col];
  red[ch][l] = s;
  __syncthreads();
  if (ch == 0) go[col] = 0.1f*(((red[0][l] + red[1][l]) + red[2][l]) + red[3][l]);
}

// ---------------- phase D: gf partials over b-chunks ----------------
__global__ __launch_bounds__(256) void k_gf(const float* __restrict__ M, const float* __restrict__ x,
                                            const int* __restrict__ tmax,
                                            float* __restrict__ gfp) {
  const int lane = threadIdx.x & 63, w = threadIdx.x >> 6;
  const int r  = blockIdx.x*64 + lane;
  const int i0 = blockIdx.y*64 + w*16;
  const int ch = blockIdx.z;
  const int b_lo = ch * (BB/NCH);
  __shared__ int cnt_sh[BB/NCH];
  if (threadIdx.x < BB/NCH) cnt_sh[threadIdx.x] = tmax[b_lo + threadIdx.x];
  __syncthreads();
  float acc[16];
  #pragma unroll
  for (int ii = 0; ii < 16; ++ii) acc[ii] = 0.f;
  int xi = i0 + (lane & 15); if (xi > N_IN - 1) xi = N_IN - 1;
  for (int bi = 0; bi < BB/NCH; ++bi) {
    const int ct = cnt_sh[bi];
    if (ct == 0) continue;
    const size_t kb = (size_t)(b_lo + bi)*TT;
    float mv = M[kb*N_HID + r];
    float xv = x[kb*N_IN + xi];
    for (int t = 0; t < ct; ++t) {
      float mv_n = 0.f, xv_n = 0.f;
      if (t + 1 < ct) {
        mv_n = M[(kb + t + 1)*N_HID + r];
        xv_n = x[(kb + t + 1)*N_IN + xi];
      }
      #pragma unroll
      for (int ii = 0; ii < 16; ++ii) acc[ii] += mv * __shfl(xv, ii);
      mv = mv_n; xv = xv_n;
    }
  }
  #pragma unroll
  for (int ii = 0; ii < 16; ++ii) {
    const int i = i0 + ii;
    if (i < N_IN) gfp[(size_t)ch*(N_HID*N_IN) + (size_t)r*N_IN + i] = acc[ii];
  }
}

// ---------------- phase D: gr partials over b-chunks ----------------
__global__ __launch_bounds__(256) void k_gr(const float* __restrict__ M,
                                            const unsigned long long* __restrict__ hsbits,
                                            const int* __restrict__ tmax,
                                            float* __restrict__ grp) {
  const int lane = threadIdx.x & 63, w = threadIdx.x >> 6;
  const int r  = blockIdx.x*64 + lane;
  const int h0 = blockIdx.y*64 + w*16;
  const int ch = blockIdx.z;
  const int b_lo = ch * (BB/NCH);
  __shared__ int cnt_sh[BB/NCH];
  if (threadIdx.x < BB/NCH) cnt_sh[threadIdx.x] = tmax[b_lo + threadIdx.x];
  __syncthreads();
  float acc[16];
  #pragma unroll
  for (int ii = 0; ii < 16; ++ii) acc[ii] = 0.f;
  const int hw = h0 >> 6, sh = h0 & 63;
  for (int bi = 0; bi < BB/NCH; ++bi) {
    const int ct = cnt_sh[bi];
    if (ct == 0) continue;
    const size_t kb = (size_t)(b_lo + bi)*TT;
    float mv = M[kb*N_HID + r];
    unsigned long long word = hsbits[kb*8 + hw];
    for (int t = 0; t < ct; ++t) {
      float mv_n = 0.f; unsigned long long word_n = 0ULL;
      if (t + 1 < ct) {
        mv_n = M[(kb + t + 1)*N_HID + r];
        word_n = hsbits[(kb + t + 1)*8 + hw];
      }
      #pragma unroll
      for (int ii = 0; ii < 16; ++ii)
        if ((word >> (sh + ii)) & 1ULL) acc[ii] += mv;
      mv = mv_n; word = word_n;
    }
  }
  #pragma unroll
  for (int ii = 0; ii < 16; ++ii)
    grp[(size_t)ch*(N_HID*N_HID) + (size_t)r*N_HID + h0 + ii] = acc[ii];
}

// ---------------- phase D: deterministic partial reductions ----------------
__global__ void k_gfred(const float* __restrict__ gfp, float* __restrict__ gf) {
  const int g = blockIdx.x*256 + threadIdx.x;
  if (g < N_HID*N_IN) {
    float s = 0.f;
    #pragma unroll
    for (int c = 0; c < NCH; ++c) s += gfp[(size_t)c*(N_HID*N_IN) + g];
    gf[g] = 0.1f*s;
  }
}
__global__ void k_grred(const float* __restrict__ grp, float* __restrict__ gr) {
  const int g = blockIdx.x*256 + threadIdx.x;
  if (g < N_HID*N_HID) {
    float s = 0.f;
    #pragma unroll
    for (int c = 0; c < NCH; ++c) s += grp[(size_t)c*(N_HID*N_HID) + g];
    gr[g] = 0.1f*s;
  }
}

extern "C" void kernel_launch(void* const* d_in, const int* in_sizes, int n_in,
                              void* d_out, int out_size, void* d_ws, size_t ws_size,
                              hipStream_t stream) {
  const float* x     = (const float*)d_in[0];
  const float* label = (const float*)d_in[1];
  const float* W1    = (const float*)d_in[2];
  const float* Wr    = (const float*)d_in[3];
  const float* Wo    = (const float*)d_in[4];

  float* out  = (float*)d_out;
  float* outs = out;                                    // [256][100][20]
  float* gf   = out + 512000;                           // [512][700]
  float* gr   = out + 512000 + 358400;                  // [512][512]
  float* go   = out + 512000 + 358400 + 262144;         // [20][512]

  char* ws = (char*)d_ws;
  size_t off = 0;
  auto alloc = [&](size_t bytes) -> char* {
    char* p = ws + off;
    off += (bytes + 255) & ~(size_t)255;
    return p;
  };
  float* INL = (float*)alloc((size_t)NK*N_HID*sizeof(float));                    // 52.43 MB
  unsigned long long* hsb = (unsigned long long*)alloc((size_t)NK*8*sizeof(unsigned long long)); // 1.64 MB
  int* tmax = (int*)alloc((size_t)BB*sizeof(int));
  char* uni = alloc((size_t)20971520);                                           // 20 MB union region

  // early residents of uni (all dead before k_gf):
  unsigned short* WH = (unsigned short*)(uni);          // 0.72 MB  (dead after gemm)
  unsigned short* WL = (unsigned short*)(uni + 720896); // 0.72 MB  (dead after gemm)
  float* WRT  = (float*)(uni + 1441792);                // 1.05 MB  (dead after scan)
  float* Srow = (float*)(uni + 2490368);
  float* SOs  = (float*)(uni + 2492416);
  float* WoT  = (float*)(uni + 2494464);                // 40 KB    (dead after scan)
  float* errb = (float*)(uni + 2536448);                // 2.05 MB  (scan -> mfilter)
  float* pgo  = (float*)(uni + 4587520);                // 10.49 MB (mfilter -> k_go)
  // late residents:
  float* gfp  = (float*)(uni);                          // 11.47 MB (k_gf)
  float* grp  = (float*)(uni + 11468800);               // 8.39 MB  (k_gr)

  k_wsplit<<<(N_HID*88 + 255)/256, 256, 0, stream>>>(W1, WH, WL);
  k_prep_t2<<<(N_HID*N_HID + 255)/256, 256, 0, stream>>>(Wr, Wo, WRT, WoT);
  k_prep_sums<<<(N_HID + N_OUT + 255)/256, 256, 0, stream>>>(Wr, Wo, Srow, SOs, tmax);
  dim3 gg(NK/128, N_HID/128);
  k_gemm<<<gg, 256, 0, stream>>>(x, WH, WL, INL);
  k_scan<<<BB, 64, 0, stream>>>(INL, label, WoT, WRT, Srow, SOs, hsb, outs, errb);
  k_mfilter<<<(BB*N_HID)/256, 256, 0, stream>>>(INL, errb, hsb, Wo, tmax, pgo);
  k_go<<<(N_OUT*N_HID)/64, 256, 0, stream>>>(pgo, go);
  dim3 ggf(8, 11, NCH); k_gf<<<ggf, 256, 0, stream>>>(INL, x, tmax, gfp);
  dim3 ggr(8, 8, NCH);  k_gr<<<ggr, 256, 0, stream>>>(INL, hsb, tmax, grp);
  k_gfred<<<(N_HID*N_IN + 255)/256, 256, 0, stream>>>(gfp, gf);
  k_grred<<<(N_HID*N_HID + 255)/256, 256, 0, stream>>>(grp, gr);
}